// Round 12
// baseline (183.677 us; speedup 1.0000x reference)
//
#include <hip/hip_runtime.h>
#include <hip/hip_bf16.h>
#include <math.h>

#define N_USERS 8000
#define N_ENTITIES 32000
#define EMB 64
#define N_GROUPS 4
#define N_EDGES 200000

// bucketed adjacency (finer buckets for occupancy; XCD-pair group affinity)
#define UBUCK 500            // 8000 users  / 16 per bucket (mean 400 edges)
#define EBUCK 1000           // 32000 ents  / 32 per bucket (mean 200 edges)
#define UCAP 640             // mean 400, +12 sigma
#define ECAP 384             // mean 200, +13 sigma
#define BIN_CHUNK 2048

typedef __attribute__((ext_vector_type(8))) __bf16 bf16x8;
typedef __attribute__((ext_vector_type(16))) float f32x16;

static __device__ __forceinline__ unsigned short f2bf(float f) {
    union { float f; unsigned int i; } x; x.f = f;
    return (unsigned short)((x.i + 0x7FFF + ((x.i >> 16) & 1)) >> 16);
}
static __device__ __forceinline__ float u2f(unsigned int u) {
    union { unsigned int i; float f; } x; x.i = u; return x.f;
}

// ---------------------------------------------------------------------------
// Convert user_emb / entity_emb to bf16 tables.
// ---------------------------------------------------------------------------
__global__ __launch_bounds__(256) void convert_tables(
    const float* __restrict__ ue, const float* __restrict__ ee,
    ushort* __restrict__ ueh, ushort* __restrict__ eeh)
{
    int i4 = blockIdx.x * 256 + threadIdx.x;   // float4 units
    if (i4 < 128000) {
        float4 v = ((const float4*)ue)[i4];
        ushort4 o; o.x = f2bf(v.x); o.y = f2bf(v.y); o.z = f2bf(v.z); o.w = f2bf(v.w);
        ((ushort4*)ueh)[i4] = o;
    } else if (i4 < 640000) {
        int j = i4 - 128000;
        float4 v = ((const float4*)ee)[j];
        ushort4 o; o.x = f2bf(v.x); o.y = f2bf(v.y); o.z = f2bf(v.z); o.w = f2bf(v.w);
        ((ushort4*)eeh)[j] = o;
    }
}

// ---------------------------------------------------------------------------
// Destination-bucketed binning, both directions, per group.
// word (user dir):  (u & 15) | (v << 4)   bucket = u >> 4   (500 buckets)
// word (ent  dir):  (v & 31) | (u << 5)   bucket = v >> 5   (1000 buckets)
// Only int atomics: LDS histogram + one global atomicAdd per (block,bucket).
// ---------------------------------------------------------------------------
__global__ __launch_bounds__(256) void bin_edges(
    const int* __restrict__ ui_index, const int* __restrict__ ei_index,
    int* __restrict__ cnt_u, int* __restrict__ cnt_e,
    int* __restrict__ bin_u, int* __restrict__ bin_e)
{
    int g = blockIdx.y;
    const int* ui = ui_index + (size_t)g * N_EDGES;
    const int* ei = ei_index + (size_t)g * N_EDGES;
    __shared__ int hU[UBUCK], hE[EBUCK], bU[UBUCK], bE[EBUCK];
    int t = threadIdx.x;
    for (int i = t; i < UBUCK; i += 256) hU[i] = 0;
    for (int i = t; i < EBUCK; i += 256) hE[i] = 0;
    __syncthreads();
    int e0 = blockIdx.x * BIN_CHUNK;
    int us[8], vs[8];
    #pragma unroll
    for (int i = 0; i < 8; ++i) {
        int e = e0 + i * 256 + t;
        bool ok = e < N_EDGES;
        us[i] = ok ? ui[e] : -1;
        vs[i] = ok ? ei[e] : 0;
        if (ok) {
            atomicAdd(&hU[us[i] >> 4], 1);
            atomicAdd(&hE[vs[i] >> 5], 1);
        }
    }
    __syncthreads();
    for (int i = t; i < UBUCK; i += 256) {
        int c = hU[i];
        bU[i] = c ? atomicAdd(&cnt_u[g * UBUCK + i], c) : 0;
        hU[i] = 0;
    }
    for (int i = t; i < EBUCK; i += 256) {
        int c = hE[i];
        bE[i] = c ? atomicAdd(&cnt_e[g * EBUCK + i], c) : 0;
        hE[i] = 0;
    }
    __syncthreads();
    #pragma unroll
    for (int i = 0; i < 8; ++i) {
        if (us[i] >= 0) {
            int bu = us[i] >> 4;
            int s = atomicAdd(&hU[bu], 1) + bU[bu];
            if (s < UCAP)
                bin_u[((size_t)g * UBUCK + bu) * UCAP + s] = (us[i] & 15) | (vs[i] << 4);
            int be = vs[i] >> 5;
            int s2 = atomicAdd(&hE[be], 1) + bE[be];
            if (s2 < ECAP)
                bin_e[((size_t)g * EBUCK + be) * ECAP + s2] = (vs[i] & 31) | (us[i] << 5);
        }
    }
}

// ---------------------------------------------------------------------------
// group/bucket mapping: affin -> flat grid with XCD-pair group affinity
// ---------------------------------------------------------------------------
static __device__ __forceinline__ void map_gb(int gbase, int affin, int& g, int& b)
{
    if (affin) {
        int bid = blockIdx.x;
        int xcd = bid & 7;
        g = xcd >> 1;
        b = ((bid >> 3) << 1) | (xcd & 1);
    } else {
        g = gbase + blockIdx.y;
        b = blockIdx.x;
    }
}

// ---------------------------------------------------------------------------
// Entity hop0, bucketed: counting-sort in LDS (int atomics only), then per
// destination row quad-slot register accumulation, l2norm, bf16 store.
// ---------------------------------------------------------------------------
__global__ __launch_bounds__(256) void agg_entity_b(
    const int* __restrict__ cnt_e, const int* __restrict__ bin_e,
    const ushort* __restrict__ ueh, ushort* __restrict__ ebufh,
    int gbase, int affin)
{
    int g, b;
    map_gb(gbase, affin, g, b);
    int gz = g - gbase;
    __shared__ int wds[ECAP];
    __shared__ int srt[ECAP];
    __shared__ int cnt[32];
    __shared__ int ptr[33];
    __shared__ int cur[32];
    int t = threadIdx.x;
    int count = min(cnt_e[g * EBUCK + b], ECAP);
    const int* bin = bin_e + ((size_t)g * EBUCK + b) * ECAP;
    if (t < 32) cnt[t] = 0;
    __syncthreads();
    for (int i = t; i < count; i += 256) {
        int w_ = bin[i];
        wds[i] = w_;
        atomicAdd(&cnt[w_ & 31], 1);
    }
    __syncthreads();
    if (t == 0) {
        int run = 0;
        for (int i = 0; i < 32; ++i) { ptr[i] = run; run += cnt[i]; }
        ptr[32] = run;
    }
    __syncthreads();
    if (t < 32) cur[t] = ptr[t];
    __syncthreads();
    for (int i = t; i < count; i += 256) {
        int w_ = wds[i];
        int pos = atomicAdd(&cur[w_ & 31], 1);
        srt[pos] = w_ >> 5;
    }
    __syncthreads();
    int wv = t >> 6, lane = t & 63, q = lane >> 4, d16 = lane & 15;
    for (int r = wv; r < 32; r += 4) {
        int start = ptr[r], end = ptr[r + 1];
        float a0 = 0.f, a1 = 0.f, a2 = 0.f, a3 = 0.f;
        for (int base = start; base < end; base += 4) {
            int idx = base + q;
            int src = idx < end ? srt[idx] : -1;
            unsigned sidx = src >= 0 ? (unsigned)src : 0u;
            uint2 r2 = *(const uint2*)(ueh + (sidx << 6) + (d16 << 2));
            if (src < 0) { r2.x = 0u; r2.y = 0u; }
            a0 += u2f(r2.x << 16);
            a1 += u2f(r2.x & 0xFFFF0000u);
            a2 += u2f(r2.y << 16);
            a3 += u2f(r2.y & 0xFFFF0000u);
        }
        a0 += __shfl_xor(a0, 16); a0 += __shfl_xor(a0, 32);
        a1 += __shfl_xor(a1, 16); a1 += __shfl_xor(a1, 32);
        a2 += __shfl_xor(a2, 16); a2 += __shfl_xor(a2, 32);
        a3 += __shfl_xor(a3, 16); a3 += __shfl_xor(a3, 32);
        float ss = a0 * a0 + a1 * a1 + a2 * a2 + a3 * a3;
        #pragma unroll
        for (int off = 1; off < 16; off <<= 1) ss += __shfl_xor(ss, off);
        float inv = 1.0f / fmaxf(sqrtf(ss), 1e-12f);
        if (lane < 16) {
            ushort4 o;
            o.x = f2bf(a0 * inv); o.y = f2bf(a1 * inv);
            o.z = f2bf(a2 * inv); o.w = f2bf(a3 * inv);
            *(ushort4*)(ebufh + (size_t)gz * N_ENTITIES * EMB
                        + (((size_t)b * 32 + r) << 6) + (d16 << 2)) = o;
        }
    }
}

// ---------------------------------------------------------------------------
// User hop0+hop1 fused, bucketed: counting-sort, then per row gather BOTH
// eeh and ebufh rows per edge slot; acc = norm(A) + norm(B).
// ---------------------------------------------------------------------------
__global__ __launch_bounds__(256) void agg_user_b(
    const int* __restrict__ cnt_u, const int* __restrict__ bin_u,
    const ushort* __restrict__ eeh, const ushort* __restrict__ ebufh,
    float* __restrict__ acc, int gbase, int affin)
{
    int g, b;
    map_gb(gbase, affin, g, b);
    int gz = g - gbase;
    __shared__ int wds[UCAP];
    __shared__ int srt[UCAP];
    __shared__ int cnt[16];
    __shared__ int ptr[17];
    __shared__ int cur[16];
    int t = threadIdx.x;
    int count = min(cnt_u[g * UBUCK + b], UCAP);
    const int* bin = bin_u + ((size_t)g * UBUCK + b) * UCAP;
    const ushort* tabB = ebufh + (size_t)gz * N_ENTITIES * EMB;
    if (t < 16) cnt[t] = 0;
    __syncthreads();
    for (int i = t; i < count; i += 256) {
        int w_ = bin[i];
        wds[i] = w_;
        atomicAdd(&cnt[w_ & 15], 1);
    }
    __syncthreads();
    if (t == 0) {
        int run = 0;
        for (int i = 0; i < 16; ++i) { ptr[i] = run; run += cnt[i]; }
        ptr[16] = run;
    }
    __syncthreads();
    if (t < 16) cur[t] = ptr[t];
    __syncthreads();
    for (int i = t; i < count; i += 256) {
        int w_ = wds[i];
        int pos = atomicAdd(&cur[w_ & 15], 1);
        srt[pos] = w_ >> 4;
    }
    __syncthreads();
    int wv = t >> 6, lane = t & 63, q = lane >> 4, d16 = lane & 15;
    for (int r = wv; r < 16; r += 4) {
        int start = ptr[r], end = ptr[r + 1];
        float a0 = 0.f, a1 = 0.f, a2 = 0.f, a3 = 0.f;
        float b0 = 0.f, b1_ = 0.f, b2_ = 0.f, b3 = 0.f;
        for (int base = start; base < end; base += 4) {
            int idx = base + q;
            int src = idx < end ? srt[idx] : -1;
            unsigned sidx = src >= 0 ? (unsigned)src : 0u;
            unsigned off = (sidx << 6) + (d16 << 2);
            uint2 ra = *(const uint2*)(eeh + off);
            uint2 rb = *(const uint2*)(tabB + off);
            if (src < 0) { ra.x = 0u; ra.y = 0u; rb.x = 0u; rb.y = 0u; }
            a0 += u2f(ra.x << 16);
            a1 += u2f(ra.x & 0xFFFF0000u);
            a2 += u2f(ra.y << 16);
            a3 += u2f(ra.y & 0xFFFF0000u);
            b0  += u2f(rb.x << 16);
            b1_ += u2f(rb.x & 0xFFFF0000u);
            b2_ += u2f(rb.y << 16);
            b3  += u2f(rb.y & 0xFFFF0000u);
        }
        a0 += __shfl_xor(a0, 16); a0 += __shfl_xor(a0, 32);
        a1 += __shfl_xor(a1, 16); a1 += __shfl_xor(a1, 32);
        a2 += __shfl_xor(a2, 16); a2 += __shfl_xor(a2, 32);
        a3 += __shfl_xor(a3, 16); a3 += __shfl_xor(a3, 32);
        b0  += __shfl_xor(b0, 16);  b0  += __shfl_xor(b0, 32);
        b1_ += __shfl_xor(b1_, 16); b1_ += __shfl_xor(b1_, 32);
        b2_ += __shfl_xor(b2_, 16); b2_ += __shfl_xor(b2_, 32);
        b3  += __shfl_xor(b3, 16);  b3  += __shfl_xor(b3, 32);
        float ssA = a0 * a0 + a1 * a1 + a2 * a2 + a3 * a3;
        float ssB = b0 * b0 + b1_ * b1_ + b2_ * b2_ + b3 * b3;
        #pragma unroll
        for (int off = 1; off < 16; off <<= 1) {
            ssA += __shfl_xor(ssA, off);
            ssB += __shfl_xor(ssB, off);
        }
        float invA = 1.0f / fmaxf(sqrtf(ssA), 1e-12f);
        float invB = 1.0f / fmaxf(sqrtf(ssB), 1e-12f);
        if (lane < 16) {
            float4 o;
            o.x = a0 * invA + b0 * invB;
            o.y = a1 * invA + b1_ * invB;
            o.z = a2 * invA + b2_ * invB;
            o.w = a3 * invA + b3 * invB;
            *(float4*)(acc + (size_t)g * N_USERS * EMB
                       + (((size_t)b * 16 + r) << 6) + (d16 << 2)) = o;
        }
    }
}

// ---------------------------------------------------------------------------
// Fused: attention-combine -> out_user; proj+normalize of (uie, out_user)
// -> bf16 p1h/p2h; diag = 2*dot(n0,n1).
// ---------------------------------------------------------------------------
__global__ __launch_bounds__(256) void combine_proj(
    const float* __restrict__ acc, const float* __restrict__ uie,
    const float* __restrict__ uemb,
    const float* __restrict__ W1, const float* __restrict__ b1,
    const float* __restrict__ W2, const float* __restrict__ b2,
    float* __restrict__ out_user,
    ushort* __restrict__ p1h, ushort* __restrict__ p2h,
    float* __restrict__ diag)
{
    __shared__ float W1s[EMB * EMB];
    __shared__ float W2s[EMB * EMB];
    __shared__ float zs[4][2][EMB];
    __shared__ float hs[4][2][EMB];
    int t = threadIdx.x;
    for (int i = t; i < EMB * EMB; i += 256) { W1s[i] = W1[i]; W2s[i] = W2[i]; }
    int w = t >> 6, lane = t & 63;
    int u = blockIdx.x * 4 + w;

    float ue = uie[(u << 6) + lane];
    float av[N_GROUPS], s[N_GROUPS];
    #pragma unroll
    for (int g = 0; g < N_GROUPS; ++g) {
        av[g] = acc[(size_t)g * N_USERS * EMB + (u << 6) + lane];
        float p = av[g] * ue;
        #pragma unroll
        for (int off = 1; off < 64; off <<= 1) p += __shfl_xor(p, off);
        s[g] = p;
    }
    float m = fmaxf(fmaxf(s[0], s[1]), fmaxf(s[2], s[3]));
    float att[N_GROUPS], tot = 0.f;
    #pragma unroll
    for (int g = 0; g < N_GROUPS; ++g) { att[g] = __expf(s[g] - m); tot += att[g]; }
    float inv = 1.0f / tot;
    float o = uemb[(u << 6) + lane];
    #pragma unroll
    for (int g = 0; g < N_GROUPS; ++g) o += att[g] * inv * av[g];
    out_user[(u << 6) + lane] = o;

    zs[w][0][lane] = ue;
    zs[w][1][lane] = o;
    __syncthreads();
    float h0 = b1[lane], h1 = b1[lane];
    #pragma unroll
    for (int k = 0; k < EMB; ++k) {
        float w1 = W1s[k * EMB + lane];
        h0 = fmaf(zs[w][0][k], w1, h0);
        h1 = fmaf(zs[w][1][k], w1, h1);
    }
    h0 = h0 > 0.f ? h0 : expm1f(h0);
    h1 = h1 > 0.f ? h1 : expm1f(h1);
    hs[w][0][lane] = h0;
    hs[w][1][lane] = h1;
    __syncthreads();
    float y0 = b2[lane], y1 = b2[lane];
    #pragma unroll
    for (int k = 0; k < EMB; ++k) {
        float w2 = W2s[k * EMB + lane];
        y0 = fmaf(hs[w][0][k], w2, y0);
        y1 = fmaf(hs[w][1][k], w2, y1);
    }
    float ss0 = y0 * y0, ss1 = y1 * y1;
    #pragma unroll
    for (int off = 1; off < 64; off <<= 1) {
        ss0 += __shfl_xor(ss0, off);
        ss1 += __shfl_xor(ss1, off);
    }
    float n0 = y0 / fmaxf(sqrtf(ss0), 1e-12f);
    float n1 = y1 / fmaxf(sqrtf(ss1), 1e-12f);
    p1h[(u << 6) + lane] = f2bf(n0);
    p2h[(u << 6) + lane] = f2bf(n1);
    float d = n0 * n1;
    #pragma unroll
    for (int off = 1; off < 64; off <<= 1) d += __shfl_xor(d, off);
    if (lane == 0) diag[u] = d * 2.0f;
}

// ---------------------------------------------------------------------------
// MFMA LSE: one traversal of logits = 2 * A@B^T -> row & col exp-sum partials.
// NCHUNK=50 (5 tiles/wave, 12500 waves) for TLP; B fragments double-buffered
// in registers so the next tile's gather hides under this tile's MFMA+exp.
// ---------------------------------------------------------------------------
#define NCHUNK 50
#define TILES_PER_CHUNK 5
#define NWAVES (250 * NCHUNK)
__global__ __launch_bounds__(256) void lse_mfma(
    const ushort* __restrict__ Ah, const ushort* __restrict__ Bh,
    float* __restrict__ rowp, float* __restrict__ colp)
{
    int W = blockIdx.x * 4 + (threadIdx.x >> 6);
    int lane = threadIdx.x & 63;
    int strip = W / NCHUNK;
    int chunk = W % NCHUNK;
    int i0 = strip * 32;
    int hl = lane >> 5;
    int l31 = lane & 31;

    const bf16x8* A8 = (const bf16x8*)Ah;
    const bf16x8* B8 = (const bf16x8*)Bh;

    bf16x8 afrag[4];
    #pragma unroll
    for (int m = 0; m < 4; ++m)
        afrag[m] = A8[(i0 + l31) * 8 + m * 2 + hl];

    float rowacc[16];
    #pragma unroll
    for (int r = 0; r < 16; ++r) rowacc[r] = 0.f;

    int j0 = chunk * (TILES_PER_CHUNK * 32);
    bf16x8 bcur[4], bnxt[4];
    #pragma unroll
    for (int m = 0; m < 4; ++m)
        bcur[m] = B8[(j0 + l31) * 8 + m * 2 + hl];

    for (int tj = 0; tj < TILES_PER_CHUNK; ++tj) {
        int jt = j0 + tj * 32;
        if (tj < TILES_PER_CHUNK - 1) {
            int jn = jt + 32;
            #pragma unroll
            for (int m = 0; m < 4; ++m)
                bnxt[m] = B8[(jn + l31) * 8 + m * 2 + hl];
        }
        f32x16 acc;
        #pragma unroll
        for (int r = 0; r < 16; ++r) acc[r] = 0.f;
        #pragma unroll
        for (int m = 0; m < 4; ++m)
            acc = __builtin_amdgcn_mfma_f32_32x32x16_bf16(afrag[m], bcur[m], acc, 0, 0, 0);
        float e[16];
        #pragma unroll
        for (int r = 0; r < 16; ++r) {
            e[r] = __expf(acc[r] * 2.0f);
            rowacc[r] += e[r];
        }
        // tree-reduce the 16 exps for the column sums
        float c01 = (e[0] + e[1]) + (e[2] + e[3]);
        float c23 = (e[4] + e[5]) + (e[6] + e[7]);
        float c45 = (e[8] + e[9]) + (e[10] + e[11]);
        float c67 = (e[12] + e[13]) + (e[14] + e[15]);
        float csum = (c01 + c23) + (c45 + c67);
        csum += __shfl_xor(csum, 32);
        if (lane < 32) colp[strip * 8000 + jt + lane] = csum;
        #pragma unroll
        for (int m = 0; m < 4; ++m) bcur[m] = bnxt[m];
    }
    #pragma unroll
    for (int r = 0; r < 16; ++r) {
        float v = rowacc[r];
        #pragma unroll
        for (int off = 1; off < 32; off <<= 1) v += __shfl_xor(v, off);
        if (l31 == 0)
            rowp[chunk * 8000 + i0 + (r & 3) + 8 * (r >> 2) + 4 * hl] = v;
    }
}

// ---------------------------------------------------------------------------
// se_row[i] = sum_c rowp[c][i]; se_col[j] = sum_s colp[s][j]
// ---------------------------------------------------------------------------
__global__ __launch_bounds__(256) void reduce_partials(
    const float* __restrict__ rowp, const float* __restrict__ colp,
    float* __restrict__ se_row, float* __restrict__ se_col)
{
    int id = blockIdx.x * 256 + threadIdx.x;
    if (id < N_USERS) {
        float s = 0.f;
        for (int c = 0; c < NCHUNK; ++c) s += rowp[c * 8000 + id];
        se_row[id] = s;
    } else if (id < 2 * N_USERS) {
        int j = id - N_USERS;
        float s = 0.f;
        for (int st = 0; st < 250; ++st) s += colp[st * 8000 + j];
        se_col[j] = s;
    }
}

// ---------------------------------------------------------------------------
// loss = mean_i( 0.5*(log(se_row)+log(se_col)) - diag )
// ---------------------------------------------------------------------------
__global__ __launch_bounds__(256) void loss_kernel(
    const float* __restrict__ se_row, const float* __restrict__ se_col,
    const float* __restrict__ diag, float* __restrict__ out)
{
    __shared__ float red[256];
    int t = threadIdx.x;
    float s = 0.f;
    for (int i = t; i < N_USERS; i += 256)
        s += 0.5f * (logf(se_row[i]) + logf(se_col[i])) - diag[i];
    red[t] = s;
    __syncthreads();
    for (int w = 128; w > 0; w >>= 1) {
        if (t < w) red[t] += red[t + w];
        __syncthreads();
    }
    if (t == 0) out[0] = red[0] / (float)N_USERS;
}

extern "C" void kernel_launch(void* const* d_in, const int* in_sizes, int n_in,
                              void* d_out, int out_size, void* d_ws, size_t ws_size,
                              hipStream_t stream)
{
    const float* user_emb   = (const float*)d_in[0];
    const float* user_ui    = (const float*)d_in[1];
    const float* entity_emb = (const float*)d_in[2];
    const float* W1 = (const float*)d_in[3];
    const float* b1 = (const float*)d_in[4];
    const float* W2 = (const float*)d_in[5];
    const float* b2 = (const float*)d_in[6];
    const int* ui_index = (const int*)d_in[7];
    const int* ei_index = (const int*)d_in[8];

    float* ws = (float*)d_ws;
    // Layout (float units). Lifetimes stream-ordered; overlays noted.
    float* acc    = ws;                        // [0, 2,048,000) dead after combine_proj
    float* colp   = acc;                       //   overlay: lse col partials (2,000,000)
    float* se_row = ws + 2048000;              // 8,000
    float* se_col = se_row + 8000;             // 8,000
    float* diag   = se_col + 8000;             // 8,000  (ends 2,072,000)
    ushort* p1h = (ushort*)(ws + 2072000);     // 512,000 ushort
    ushort* p2h = (ushort*)(ws + 2328000);     // 512,000 ushort
    float* rowp = ws + 2584000;                // 50*8000 = 400,000 -> ends 2,984,000
    int* cnt_u = (int*)(ws + 2984000);         // 4*500 = 2,000
    int* cnt_e = cnt_u + N_GROUPS * UBUCK;     // 4*1000 = 4,000 (ends 2,990,000)
    int* bin_u = cnt_e + N_GROUPS * EBUCK;     // 4*500*640 = 1,280,000 (ends 4,270,000)
    int* bin_e = bin_u + N_GROUPS * UBUCK * UCAP; // 4*1000*384 = 1,536,000 (ends 5,806,000)
    ushort* ueh = (ushort*)(ws + 5806000);     // 512,000 ushort (256,000 f)
    ushort* eeh = (ushort*)(ws + 6062000);     // 2,048,000 ushort (ends 7,086,000)
    ushort* ebufh = (ushort*)(ws + 7086000);   // nG * 2,048,000 ushort

    const size_t BASE_F = 7086000;
    int nG = 1;
    if (ws_size >= (BASE_F + 4 * 1024000) * 4) nG = 4;       // 44.7 MB
    else if (ws_size >= (BASE_F + 2 * 1024000) * 4) nG = 2;  // 36.5 MB

    float* out_user = (float*)d_out;           // 512,000
    float* out_loss = out_user + 512000;       // 1

    dim3 b256(256);

    hipMemsetAsync(cnt_u, 0, (size_t)N_GROUPS * (UBUCK + EBUCK) * 4, stream);
    convert_tables<<<2500, b256, 0, stream>>>(user_emb, entity_emb, ueh, eeh);
    bin_edges<<<dim3((N_EDGES + BIN_CHUNK - 1) / BIN_CHUNK, N_GROUPS), b256, 0, stream>>>(
        ui_index, ei_index, cnt_u, cnt_e, bin_u, bin_e);

    if (nG == 4) {
        // flat grids with XCD-pair group affinity
        agg_entity_b<<<EBUCK * 4, b256, 0, stream>>>(
            cnt_e, bin_e, ueh, ebufh, 0, 1);
        agg_user_b<<<UBUCK * 4, b256, 0, stream>>>(
            cnt_u, bin_u, eeh, ebufh, acc, 0, 1);
    } else {
        for (int gbase = 0; gbase < N_GROUPS; gbase += nG) {
            agg_entity_b<<<dim3(EBUCK, nG), b256, 0, stream>>>(
                cnt_e, bin_e, ueh, ebufh, gbase, 0);
            agg_user_b<<<dim3(UBUCK, nG), b256, 0, stream>>>(
                cnt_u, bin_u, eeh, ebufh, acc, gbase, 0);
        }
    }

    combine_proj<<<N_USERS / 4, b256, 0, stream>>>(
        acc, user_ui, user_emb, W1, b1, W2, b2,
        out_user, p1h, p2h, diag);

    lse_mfma<<<NWAVES / 4, b256, 0, stream>>>(p1h, p2h, rowp, colp);
    reduce_partials<<<(2 * N_USERS + 255) / 256, b256, 0, stream>>>(
        rowp, colp, se_row, se_col);
    loss_kernel<<<1, b256, 0, stream>>>(se_row, se_col, diag, out_loss);
}

// Round 14
// 172.584 us; speedup vs baseline: 1.0643x; 1.0643x over previous
//
#include <hip/hip_runtime.h>
#include <hip/hip_bf16.h>
#include <math.h>

#define N_USERS 8000
#define N_ENTITIES 32000
#define EMB 64
#define N_GROUPS 4
#define N_EDGES 200000

// bucketed adjacency (finer buckets for occupancy; XCD-pair group affinity)
#define UBUCK 500            // 8000 users  / 16 per bucket (mean 400 edges)
#define EBUCK 1000           // 32000 ents  / 32 per bucket (mean 200 edges)
#define UCAP 640             // mean 400, +12 sigma
#define ECAP 384             // mean 200, +13 sigma
#define BIN_CHUNK 2048

typedef __attribute__((ext_vector_type(8))) __bf16 bf16x8;
typedef __attribute__((ext_vector_type(16))) float f32x16;

static __device__ __forceinline__ unsigned short f2bf(float f) {
    union { float f; unsigned int i; } x; x.f = f;
    return (unsigned short)((x.i + 0x7FFF + ((x.i >> 16) & 1)) >> 16);
}
static __device__ __forceinline__ float u2f(unsigned int u) {
    union { unsigned int i; float f; } x; x.i = u; return x.f;
}

// ---------------------------------------------------------------------------
// Convert user_emb / entity_emb to bf16 tables.
// ---------------------------------------------------------------------------
__global__ __launch_bounds__(256) void convert_tables(
    const float* __restrict__ ue, const float* __restrict__ ee,
    ushort* __restrict__ ueh, ushort* __restrict__ eeh)
{
    int i4 = blockIdx.x * 256 + threadIdx.x;   // float4 units
    if (i4 < 128000) {
        float4 v = ((const float4*)ue)[i4];
        ushort4 o; o.x = f2bf(v.x); o.y = f2bf(v.y); o.z = f2bf(v.z); o.w = f2bf(v.w);
        ((ushort4*)ueh)[i4] = o;
    } else if (i4 < 640000) {
        int j = i4 - 128000;
        float4 v = ((const float4*)ee)[j];
        ushort4 o; o.x = f2bf(v.x); o.y = f2bf(v.y); o.z = f2bf(v.z); o.w = f2bf(v.w);
        ((ushort4*)eeh)[j] = o;
    }
}

// ---------------------------------------------------------------------------
// Destination-bucketed binning, both directions, per group.
// word (user dir):  (u & 15) | (v << 4)   bucket = u >> 4   (500 buckets)
// word (ent  dir):  (v & 31) | (u << 5)   bucket = v >> 5   (1000 buckets)
// ---------------------------------------------------------------------------
__global__ __launch_bounds__(256) void bin_edges(
    const int* __restrict__ ui_index, const int* __restrict__ ei_index,
    int* __restrict__ cnt_u, int* __restrict__ cnt_e,
    int* __restrict__ bin_u, int* __restrict__ bin_e)
{
    int g = blockIdx.y;
    const int* ui = ui_index + (size_t)g * N_EDGES;
    const int* ei = ei_index + (size_t)g * N_EDGES;
    __shared__ int hU[UBUCK], hE[EBUCK], bU[UBUCK], bE[EBUCK];
    int t = threadIdx.x;
    for (int i = t; i < UBUCK; i += 256) hU[i] = 0;
    for (int i = t; i < EBUCK; i += 256) hE[i] = 0;
    __syncthreads();
    int e0 = blockIdx.x * BIN_CHUNK;
    int us[8], vs[8];
    #pragma unroll
    for (int i = 0; i < 8; ++i) {
        int e = e0 + i * 256 + t;
        bool ok = e < N_EDGES;
        us[i] = ok ? ui[e] : -1;
        vs[i] = ok ? ei[e] : 0;
        if (ok) {
            atomicAdd(&hU[us[i] >> 4], 1);
            atomicAdd(&hE[vs[i] >> 5], 1);
        }
    }
    __syncthreads();
    for (int i = t; i < UBUCK; i += 256) {
        int c = hU[i];
        bU[i] = c ? atomicAdd(&cnt_u[g * UBUCK + i], c) : 0;
        hU[i] = 0;
    }
    for (int i = t; i < EBUCK; i += 256) {
        int c = hE[i];
        bE[i] = c ? atomicAdd(&cnt_e[g * EBUCK + i], c) : 0;
        hE[i] = 0;
    }
    __syncthreads();
    #pragma unroll
    for (int i = 0; i < 8; ++i) {
        if (us[i] >= 0) {
            int bu = us[i] >> 4;
            int s = atomicAdd(&hU[bu], 1) + bU[bu];
            if (s < UCAP)
                bin_u[((size_t)g * UBUCK + bu) * UCAP + s] = (us[i] & 15) | (vs[i] << 4);
            int be = vs[i] >> 5;
            int s2 = atomicAdd(&hE[be], 1) + bE[be];
            if (s2 < ECAP)
                bin_e[((size_t)g * EBUCK + be) * ECAP + s2] = (vs[i] & 31) | (us[i] << 5);
        }
    }
}

// ---------------------------------------------------------------------------
// group/bucket mapping: affin -> flat grid with XCD-pair group affinity
// ---------------------------------------------------------------------------
static __device__ __forceinline__ void map_gb(int gbase, int affin, int& g, int& b)
{
    if (affin) {
        int bid = blockIdx.x;
        int xcd = bid & 7;
        g = xcd >> 1;
        b = ((bid >> 3) << 1) | (xcd & 1);
    } else {
        g = gbase + blockIdx.y;
        b = blockIdx.x;
    }
}

// ---------------------------------------------------------------------------
// Entity hop0, bucketed: counting-sort in LDS (int atomics only), then per
// destination row quad-slot register accumulation, l2norm, bf16 store.
// ---------------------------------------------------------------------------
__global__ __launch_bounds__(256) void agg_entity_b(
    const int* __restrict__ cnt_e, const int* __restrict__ bin_e,
    const ushort* __restrict__ ueh, ushort* __restrict__ ebufh,
    int gbase, int affin)
{
    int g, b;
    map_gb(gbase, affin, g, b);
    int gz = g - gbase;
    __shared__ int wds[ECAP];
    __shared__ int srt[ECAP];
    __shared__ int cnt[32];
    __shared__ int ptr[33];
    __shared__ int cur[32];
    int t = threadIdx.x;
    int count = min(cnt_e[g * EBUCK + b], ECAP);
    const int* bin = bin_e + ((size_t)g * EBUCK + b) * ECAP;
    if (t < 32) cnt[t] = 0;
    __syncthreads();
    for (int i = t; i < count; i += 256) {
        int w_ = bin[i];
        wds[i] = w_;
        atomicAdd(&cnt[w_ & 31], 1);
    }
    __syncthreads();
    if (t == 0) {
        int run = 0;
        for (int i = 0; i < 32; ++i) { ptr[i] = run; run += cnt[i]; }
        ptr[32] = run;
    }
    __syncthreads();
    if (t < 32) cur[t] = ptr[t];
    __syncthreads();
    for (int i = t; i < count; i += 256) {
        int w_ = wds[i];
        int pos = atomicAdd(&cur[w_ & 31], 1);
        srt[pos] = w_ >> 5;
    }
    __syncthreads();
    int wv = t >> 6, lane = t & 63, q = lane >> 4, d16 = lane & 15;
    for (int r = wv; r < 32; r += 4) {
        int start = ptr[r], end = ptr[r + 1];
        float a0 = 0.f, a1 = 0.f, a2 = 0.f, a3 = 0.f;
        for (int base = start; base < end; base += 4) {
            int idx = base + q;
            int src = idx < end ? srt[idx] : -1;
            unsigned sidx = src >= 0 ? (unsigned)src : 0u;
            uint2 r2 = *(const uint2*)(ueh + (sidx << 6) + (d16 << 2));
            if (src < 0) { r2.x = 0u; r2.y = 0u; }
            a0 += u2f(r2.x << 16);
            a1 += u2f(r2.x & 0xFFFF0000u);
            a2 += u2f(r2.y << 16);
            a3 += u2f(r2.y & 0xFFFF0000u);
        }
        a0 += __shfl_xor(a0, 16); a0 += __shfl_xor(a0, 32);
        a1 += __shfl_xor(a1, 16); a1 += __shfl_xor(a1, 32);
        a2 += __shfl_xor(a2, 16); a2 += __shfl_xor(a2, 32);
        a3 += __shfl_xor(a3, 16); a3 += __shfl_xor(a3, 32);
        float ss = a0 * a0 + a1 * a1 + a2 * a2 + a3 * a3;
        #pragma unroll
        for (int off = 1; off < 16; off <<= 1) ss += __shfl_xor(ss, off);
        float inv = 1.0f / fmaxf(sqrtf(ss), 1e-12f);
        if (lane < 16) {
            ushort4 o;
            o.x = f2bf(a0 * inv); o.y = f2bf(a1 * inv);
            o.z = f2bf(a2 * inv); o.w = f2bf(a3 * inv);
            *(ushort4*)(ebufh + (size_t)gz * N_ENTITIES * EMB
                        + (((size_t)b * 32 + r) << 6) + (d16 << 2)) = o;
        }
    }
}

// ---------------------------------------------------------------------------
// User hop0+hop1 fused, bucketed: counting-sort, then per row gather BOTH
// eeh and ebufh rows per edge slot; acc = norm(A) + norm(B).
// ---------------------------------------------------------------------------
__global__ __launch_bounds__(256) void agg_user_b(
    const int* __restrict__ cnt_u, const int* __restrict__ bin_u,
    const ushort* __restrict__ eeh, const ushort* __restrict__ ebufh,
    float* __restrict__ acc, int gbase, int affin)
{
    int g, b;
    map_gb(gbase, affin, g, b);
    int gz = g - gbase;
    __shared__ int wds[UCAP];
    __shared__ int srt[UCAP];
    __shared__ int cnt[16];
    __shared__ int ptr[17];
    __shared__ int cur[16];
    int t = threadIdx.x;
    int count = min(cnt_u[g * UBUCK + b], UCAP);
    const int* bin = bin_u + ((size_t)g * UBUCK + b) * UCAP;
    const ushort* tabB = ebufh + (size_t)gz * N_ENTITIES * EMB;
    if (t < 16) cnt[t] = 0;
    __syncthreads();
    for (int i = t; i < count; i += 256) {
        int w_ = bin[i];
        wds[i] = w_;
        atomicAdd(&cnt[w_ & 15], 1);
    }
    __syncthreads();
    if (t == 0) {
        int run = 0;
        for (int i = 0; i < 16; ++i) { ptr[i] = run; run += cnt[i]; }
        ptr[16] = run;
    }
    __syncthreads();
    if (t < 16) cur[t] = ptr[t];
    __syncthreads();
    for (int i = t; i < count; i += 256) {
        int w_ = wds[i];
        int pos = atomicAdd(&cur[w_ & 15], 1);
        srt[pos] = w_ >> 4;
    }
    __syncthreads();
    int wv = t >> 6, lane = t & 63, q = lane >> 4, d16 = lane & 15;
    for (int r = wv; r < 16; r += 4) {
        int start = ptr[r], end = ptr[r + 1];
        float a0 = 0.f, a1 = 0.f, a2 = 0.f, a3 = 0.f;
        float b0 = 0.f, b1_ = 0.f, b2_ = 0.f, b3 = 0.f;
        for (int base = start; base < end; base += 4) {
            int idx = base + q;
            int src = idx < end ? srt[idx] : -1;
            unsigned sidx = src >= 0 ? (unsigned)src : 0u;
            unsigned off = (sidx << 6) + (d16 << 2);
            uint2 ra = *(const uint2*)(eeh + off);
            uint2 rb = *(const uint2*)(tabB + off);
            if (src < 0) { ra.x = 0u; ra.y = 0u; rb.x = 0u; rb.y = 0u; }
            a0 += u2f(ra.x << 16);
            a1 += u2f(ra.x & 0xFFFF0000u);
            a2 += u2f(ra.y << 16);
            a3 += u2f(ra.y & 0xFFFF0000u);
            b0  += u2f(rb.x << 16);
            b1_ += u2f(rb.x & 0xFFFF0000u);
            b2_ += u2f(rb.y << 16);
            b3  += u2f(rb.y & 0xFFFF0000u);
        }
        a0 += __shfl_xor(a0, 16); a0 += __shfl_xor(a0, 32);
        a1 += __shfl_xor(a1, 16); a1 += __shfl_xor(a1, 32);
        a2 += __shfl_xor(a2, 16); a2 += __shfl_xor(a2, 32);
        a3 += __shfl_xor(a3, 16); a3 += __shfl_xor(a3, 32);
        b0  += __shfl_xor(b0, 16);  b0  += __shfl_xor(b0, 32);
        b1_ += __shfl_xor(b1_, 16); b1_ += __shfl_xor(b1_, 32);
        b2_ += __shfl_xor(b2_, 16); b2_ += __shfl_xor(b2_, 32);
        b3  += __shfl_xor(b3, 16);  b3  += __shfl_xor(b3, 32);
        float ssA = a0 * a0 + a1 * a1 + a2 * a2 + a3 * a3;
        float ssB = b0 * b0 + b1_ * b1_ + b2_ * b2_ + b3 * b3;
        #pragma unroll
        for (int off = 1; off < 16; off <<= 1) {
            ssA += __shfl_xor(ssA, off);
            ssB += __shfl_xor(ssB, off);
        }
        float invA = 1.0f / fmaxf(sqrtf(ssA), 1e-12f);
        float invB = 1.0f / fmaxf(sqrtf(ssB), 1e-12f);
        if (lane < 16) {
            float4 o;
            o.x = a0 * invA + b0 * invB;
            o.y = a1 * invA + b1_ * invB;
            o.z = a2 * invA + b2_ * invB;
            o.w = a3 * invA + b3 * invB;
            *(float4*)(acc + (size_t)g * N_USERS * EMB
                       + (((size_t)b * 16 + r) << 6) + (d16 << 2)) = o;
        }
    }
}

// ---------------------------------------------------------------------------
// Fused: attention-combine -> out_user; proj+normalize of (uie, out_user)
// -> bf16 p1h/p2h; diag = 2*dot(n0,n1).
// ---------------------------------------------------------------------------
__global__ __launch_bounds__(256) void combine_proj(
    const float* __restrict__ acc, const float* __restrict__ uie,
    const float* __restrict__ uemb,
    const float* __restrict__ W1, const float* __restrict__ b1,
    const float* __restrict__ W2, const float* __restrict__ b2,
    float* __restrict__ out_user,
    ushort* __restrict__ p1h, ushort* __restrict__ p2h,
    float* __restrict__ diag)
{
    __shared__ float W1s[EMB * EMB];
    __shared__ float W2s[EMB * EMB];
    __shared__ float zs[4][2][EMB];
    __shared__ float hs[4][2][EMB];
    int t = threadIdx.x;
    for (int i = t; i < EMB * EMB; i += 256) { W1s[i] = W1[i]; W2s[i] = W2[i]; }
    int w = t >> 6, lane = t & 63;
    int u = blockIdx.x * 4 + w;

    float ue = uie[(u << 6) + lane];
    float av[N_GROUPS], s[N_GROUPS];
    #pragma unroll
    for (int g = 0; g < N_GROUPS; ++g) {
        av[g] = acc[(size_t)g * N_USERS * EMB + (u << 6) + lane];
        float p = av[g] * ue;
        #pragma unroll
        for (int off = 1; off < 64; off <<= 1) p += __shfl_xor(p, off);
        s[g] = p;
    }
    float m = fmaxf(fmaxf(s[0], s[1]), fmaxf(s[2], s[3]));
    float att[N_GROUPS], tot = 0.f;
    #pragma unroll
    for (int g = 0; g < N_GROUPS; ++g) { att[g] = __expf(s[g] - m); tot += att[g]; }
    float inv = 1.0f / tot;
    float o = uemb[(u << 6) + lane];
    #pragma unroll
    for (int g = 0; g < N_GROUPS; ++g) o += att[g] * inv * av[g];
    out_user[(u << 6) + lane] = o;

    zs[w][0][lane] = ue;
    zs[w][1][lane] = o;
    __syncthreads();
    float h0 = b1[lane], h1 = b1[lane];
    #pragma unroll
    for (int k = 0; k < EMB; ++k) {
        float w1 = W1s[k * EMB + lane];
        h0 = fmaf(zs[w][0][k], w1, h0);
        h1 = fmaf(zs[w][1][k], w1, h1);
    }
    h0 = h0 > 0.f ? h0 : expm1f(h0);
    h1 = h1 > 0.f ? h1 : expm1f(h1);
    hs[w][0][lane] = h0;
    hs[w][1][lane] = h1;
    __syncthreads();
    float y0 = b2[lane], y1 = b2[lane];
    #pragma unroll
    for (int k = 0; k < EMB; ++k) {
        float w2 = W2s[k * EMB + lane];
        y0 = fmaf(hs[w][0][k], w2, y0);
        y1 = fmaf(hs[w][1][k], w2, y1);
    }
    float ss0 = y0 * y0, ss1 = y1 * y1;
    #pragma unroll
    for (int off = 1; off < 64; off <<= 1) {
        ss0 += __shfl_xor(ss0, off);
        ss1 += __shfl_xor(ss1, off);
    }
    float n0 = y0 / fmaxf(sqrtf(ss0), 1e-12f);
    float n1 = y1 / fmaxf(sqrtf(ss1), 1e-12f);
    p1h[(u << 6) + lane] = f2bf(n0);
    p2h[(u << 6) + lane] = f2bf(n1);
    float d = n0 * n1;
    #pragma unroll
    for (int off = 1; off < 64; off <<= 1) d += __shfl_xor(d, off);
    if (lane == 0) diag[u] = d * 2.0f;
}

// ---------------------------------------------------------------------------
// Tiled MFMA LSE (block-cooperative, LDS-staged B).
// Block = 4 waves = 128 rows x 160 cols of logits. B-tile (160x64 bf16)
// staged into LDS with stride-68 rows (34-dword stride -> 2-way = free).
// FIXED staging: 1280 slots = 160 rows x 8 x uint4 (16 B each) -> full 128 B
// per row; each slot stores as 2 x uint2 (row stride is 8 B aligned).
// ---------------------------------------------------------------------------
#define NCHUNK 50
__global__ __launch_bounds__(256) void lse_tile(
    const ushort* __restrict__ Ah, const ushort* __restrict__ Bh,
    float* __restrict__ rowp, float* __restrict__ colp)
{
    __shared__ ushort Bs[160 * 68];
    int t = threadIdx.x;
    int cb = blockIdx.x % 50;
    int rb = blockIdx.x / 50;
    int j0 = cb * 160;
    // stage B rows j0..j0+159: 160 rows x 64 ushorts, 8 ushorts per slot
    for (int slot = t; slot < 1280; slot += 256) {
        int row = slot >> 3;
        int o8 = (slot & 7) << 3;          // ushort offset within row
        uint4 v = *(const uint4*)(Bh + (size_t)(j0 + row) * 64 + o8);
        ushort* dst = Bs + row * 68 + o8;
        *(uint2*)(dst + 0) = make_uint2(v.x, v.y);
        *(uint2*)(dst + 4) = make_uint2(v.z, v.w);
    }
    __syncthreads();
    int w = t >> 6, lane = t & 63;
    int strip = rb * 4 + w;
    if (strip >= 250) return;          // ghost strips in last row-block
    int i0 = strip * 32;
    int hl = lane >> 5, l31 = lane & 31;

    const bf16x8* A8 = (const bf16x8*)Ah;
    bf16x8 afrag[4];
    #pragma unroll
    for (int m = 0; m < 4; ++m)
        afrag[m] = A8[(i0 + l31) * 8 + m * 2 + hl];

    float rowacc[16];
    #pragma unroll
    for (int r = 0; r < 16; ++r) rowacc[r] = 0.f;

    #pragma unroll
    for (int cs = 0; cs < 5; ++cs) {
        bf16x8 bfrag[4];
        #pragma unroll
        for (int m = 0; m < 4; ++m) {
            const ushort* p = Bs + (cs * 32 + l31) * 68 + m * 16 + hl * 8;
            union { uint2 u[2]; bf16x8 f; } cv;
            cv.u[0] = *(const uint2*)p;
            cv.u[1] = *(const uint2*)(p + 4);
            bfrag[m] = cv.f;
        }
        f32x16 acc;
        #pragma unroll
        for (int r = 0; r < 16; ++r) acc[r] = 0.f;
        #pragma unroll
        for (int m = 0; m < 4; ++m)
            acc = __builtin_amdgcn_mfma_f32_32x32x16_bf16(afrag[m], bfrag[m], acc, 0, 0, 0);
        float e[16];
        #pragma unroll
        for (int r = 0; r < 16; ++r) {
            e[r] = __expf(acc[r] * 2.0f);
            rowacc[r] += e[r];
        }
        float c01 = (e[0] + e[1]) + (e[2] + e[3]);
        float c23 = (e[4] + e[5]) + (e[6] + e[7]);
        float c45 = (e[8] + e[9]) + (e[10] + e[11]);
        float c67 = (e[12] + e[13]) + (e[14] + e[15]);
        float csum = (c01 + c23) + (c45 + c67);
        csum += __shfl_xor(csum, 32);
        if (lane < 32) colp[strip * 8000 + j0 + cs * 32 + lane] = csum;
    }
    #pragma unroll
    for (int r = 0; r < 16; ++r) {
        float v = rowacc[r];
        #pragma unroll
        for (int off = 1; off < 32; off <<= 1) v += __shfl_xor(v, off);
        if (l31 == 0)
            rowp[cb * 8000 + i0 + (r & 3) + 8 * (r >> 2) + 4 * hl] = v;
    }
}

// ---------------------------------------------------------------------------
// se_row[i] = sum_c rowp[c][i]; se_col[j] = sum_s colp[s][j]
// ---------------------------------------------------------------------------
__global__ __launch_bounds__(256) void reduce_partials(
    const float* __restrict__ rowp, const float* __restrict__ colp,
    float* __restrict__ se_row, float* __restrict__ se_col)
{
    int id = blockIdx.x * 256 + threadIdx.x;
    if (id < N_USERS) {
        float s = 0.f;
        for (int c = 0; c < NCHUNK; ++c) s += rowp[c * 8000 + id];
        se_row[id] = s;
    } else if (id < 2 * N_USERS) {
        int j = id - N_USERS;
        float s = 0.f;
        for (int st = 0; st < 250; ++st) s += colp[st * 8000 + j];
        se_col[j] = s;
    }
}

// ---------------------------------------------------------------------------
// loss = mean_i( 0.5*(log(se_row)+log(se_col)) - diag )
// ---------------------------------------------------------------------------
__global__ __launch_bounds__(256) void loss_kernel(
    const float* __restrict__ se_row, const float* __restrict__ se_col,
    const float* __restrict__ diag, float* __restrict__ out)
{
    __shared__ float red[256];
    int t = threadIdx.x;
    float s = 0.f;
    for (int i = t; i < N_USERS; i += 256)
        s += 0.5f * (logf(se_row[i]) + logf(se_col[i])) - diag[i];
    red[t] = s;
    __syncthreads();
    for (int w = 128; w > 0; w >>= 1) {
        if (t < w) red[t] += red[t + w];
        __syncthreads();
    }
    if (t == 0) out[0] = red[0] / (float)N_USERS;
}

extern "C" void kernel_launch(void* const* d_in, const int* in_sizes, int n_in,
                              void* d_out, int out_size, void* d_ws, size_t ws_size,
                              hipStream_t stream)
{
    const float* user_emb   = (const float*)d_in[0];
    const float* user_ui    = (const float*)d_in[1];
    const float* entity_emb = (const float*)d_in[2];
    const float* W1 = (const float*)d_in[3];
    const float* b1 = (const float*)d_in[4];
    const float* W2 = (const float*)d_in[5];
    const float* b2 = (const float*)d_in[6];
    const int* ui_index = (const int*)d_in[7];
    const int* ei_index = (const int*)d_in[8];

    float* ws = (float*)d_ws;
    // Layout (float units). Lifetimes stream-ordered; overlays noted.
    float* acc    = ws;                        // [0, 2,048,000) dead after combine_proj
    float* colp   = acc;                       //   overlay: lse col partials (2,000,000)
    float* se_row = ws + 2048000;              // 8,000
    float* se_col = se_row + 8000;             // 8,000
    float* diag   = se_col + 8000;             // 8,000  (ends 2,072,000)
    ushort* p1h = (ushort*)(ws + 2072000);     // 512,000 ushort
    ushort* p2h = (ushort*)(ws + 2328000);     // 512,000 ushort
    float* rowp = ws + 2584000;                // 50*8000 = 400,000 -> ends 2,984,000
    int* cnt_u = (int*)(ws + 2984000);         // 4*500 = 2,000
    int* cnt_e = cnt_u + N_GROUPS * UBUCK;     // 4*1000 = 4,000 (ends 2,990,000)
    int* bin_u = cnt_e + N_GROUPS * EBUCK;     // 4*500*640 = 1,280,000 (ends 4,270,000)
    int* bin_e = bin_u + N_GROUPS * UBUCK * UCAP; // 4*1000*384 = 1,536,000 (ends 5,806,000)
    ushort* ueh = (ushort*)(ws + 5806000);     // 512,000 ushort (256,000 f)
    ushort* eeh = (ushort*)(ws + 6062000);     // 2,048,000 ushort (ends 7,086,000)
    ushort* ebufh = (ushort*)(ws + 7086000);   // nG * 2,048,000 ushort

    const size_t BASE_F = 7086000;
    int nG = 1;
    if (ws_size >= (BASE_F + 4 * 1024000) * 4) nG = 4;       // 44.7 MB
    else if (ws_size >= (BASE_F + 2 * 1024000) * 4) nG = 2;  // 36.5 MB

    float* out_user = (float*)d_out;           // 512,000
    float* out_loss = out_user + 512000;       // 1

    dim3 b256(256);

    hipMemsetAsync(cnt_u, 0, (size_t)N_GROUPS * (UBUCK + EBUCK) * 4, stream);
    convert_tables<<<2500, b256, 0, stream>>>(user_emb, entity_emb, ueh, eeh);
    bin_edges<<<dim3((N_EDGES + BIN_CHUNK - 1) / BIN_CHUNK, N_GROUPS), b256, 0, stream>>>(
        ui_index, ei_index, cnt_u, cnt_e, bin_u, bin_e);

    if (nG == 4) {
        // flat grids with XCD-pair group affinity
        agg_entity_b<<<EBUCK * 4, b256, 0, stream>>>(
            cnt_e, bin_e, ueh, ebufh, 0, 1);
        agg_user_b<<<UBUCK * 4, b256, 0, stream>>>(
            cnt_u, bin_u, eeh, ebufh, acc, 0, 1);
    } else {
        for (int gbase = 0; gbase < N_GROUPS; gbase += nG) {
            agg_entity_b<<<dim3(EBUCK, nG), b256, 0, stream>>>(
                cnt_e, bin_e, ueh, ebufh, gbase, 0);
            agg_user_b<<<dim3(UBUCK, nG), b256, 0, stream>>>(
                cnt_u, bin_u, eeh, ebufh, acc, gbase, 0);
        }
    }

    combine_proj<<<N_USERS / 4, b256, 0, stream>>>(
        acc, user_ui, user_emb, W1, b1, W2, b2,
        out_user, p1h, p2h, diag);

    lse_tile<<<63 * 50, b256, 0, stream>>>(p1h, p2h, rowp, colp);
    reduce_partials<<<(2 * N_USERS + 255) / 256, b256, 0, stream>>>(
        rowp, colp, se_row, se_col);
    loss_kernel<<<1, b256, 0, stream>>>(se_row, se_col, diag, out_loss);
}

// Round 15
// 163.390 us; speedup vs baseline: 1.1242x; 1.0563x over previous
//
#include <hip/hip_runtime.h>
#include <hip/hip_bf16.h>
#include <math.h>

#define N_USERS 8000
#define N_ENTITIES 32000
#define EMB 64
#define N_GROUPS 4
#define N_EDGES 200000

// bucketed adjacency (finer buckets for occupancy; XCD-pair group affinity)
#define UBUCK 500            // 8000 users  / 16 per bucket (mean 400 edges)
#define EBUCK 1000           // 32000 ents  / 32 per bucket (mean 200 edges)
#define UCAP 640             // mean 400, +12 sigma
#define ECAP 384             // mean 200, +13 sigma
#define BIN_CHUNK 2048
#define NRB 63               // lse row-blocks (63 x 4 strips covers 250)

typedef __attribute__((ext_vector_type(8))) __bf16 bf16x8;
typedef __attribute__((ext_vector_type(16))) float f32x16;

static __device__ __forceinline__ unsigned short f2bf(float f) {
    union { float f; unsigned int i; } x; x.f = f;
    return (unsigned short)((x.i + 0x7FFF + ((x.i >> 16) & 1)) >> 16);
}
static __device__ __forceinline__ float u2f(unsigned int u) {
    union { unsigned int i; float f; } x; x.i = u; return x.f;
}

// ---------------------------------------------------------------------------
// Convert user_emb / entity_emb to bf16 tables.
// ---------------------------------------------------------------------------
__global__ __launch_bounds__(256) void convert_tables(
    const float* __restrict__ ue, const float* __restrict__ ee,
    ushort* __restrict__ ueh, ushort* __restrict__ eeh)
{
    int i4 = blockIdx.x * 256 + threadIdx.x;   // float4 units
    if (i4 < 128000) {
        float4 v = ((const float4*)ue)[i4];
        ushort4 o; o.x = f2bf(v.x); o.y = f2bf(v.y); o.z = f2bf(v.z); o.w = f2bf(v.w);
        ((ushort4*)ueh)[i4] = o;
    } else if (i4 < 640000) {
        int j = i4 - 128000;
        float4 v = ((const float4*)ee)[j];
        ushort4 o; o.x = f2bf(v.x); o.y = f2bf(v.y); o.z = f2bf(v.z); o.w = f2bf(v.w);
        ((ushort4*)eeh)[j] = o;
    }
}

// ---------------------------------------------------------------------------
// Destination-bucketed binning, both directions, per group.
// word (user dir):  (u & 15) | (v << 4)   bucket = u >> 4   (500 buckets)
// word (ent  dir):  (v & 31) | (u << 5)   bucket = v >> 5   (1000 buckets)
// ---------------------------------------------------------------------------
__global__ __launch_bounds__(256) void bin_edges(
    const int* __restrict__ ui_index, const int* __restrict__ ei_index,
    int* __restrict__ cnt_u, int* __restrict__ cnt_e,
    int* __restrict__ bin_u, int* __restrict__ bin_e)
{
    int g = blockIdx.y;
    const int* ui = ui_index + (size_t)g * N_EDGES;
    const int* ei = ei_index + (size_t)g * N_EDGES;
    __shared__ int hU[UBUCK], hE[EBUCK], bU[UBUCK], bE[EBUCK];
    int t = threadIdx.x;
    for (int i = t; i < UBUCK; i += 256) hU[i] = 0;
    for (int i = t; i < EBUCK; i += 256) hE[i] = 0;
    __syncthreads();
    int e0 = blockIdx.x * BIN_CHUNK;
    int us[8], vs[8];
    #pragma unroll
    for (int i = 0; i < 8; ++i) {
        int e = e0 + i * 256 + t;
        bool ok = e < N_EDGES;
        us[i] = ok ? ui[e] : -1;
        vs[i] = ok ? ei[e] : 0;
        if (ok) {
            atomicAdd(&hU[us[i] >> 4], 1);
            atomicAdd(&hE[vs[i] >> 5], 1);
        }
    }
    __syncthreads();
    for (int i = t; i < UBUCK; i += 256) {
        int c = hU[i];
        bU[i] = c ? atomicAdd(&cnt_u[g * UBUCK + i], c) : 0;
        hU[i] = 0;
    }
    for (int i = t; i < EBUCK; i += 256) {
        int c = hE[i];
        bE[i] = c ? atomicAdd(&cnt_e[g * EBUCK + i], c) : 0;
        hE[i] = 0;
    }
    __syncthreads();
    #pragma unroll
    for (int i = 0; i < 8; ++i) {
        if (us[i] >= 0) {
            int bu = us[i] >> 4;
            int s = atomicAdd(&hU[bu], 1) + bU[bu];
            if (s < UCAP)
                bin_u[((size_t)g * UBUCK + bu) * UCAP + s] = (us[i] & 15) | (vs[i] << 4);
            int be = vs[i] >> 5;
            int s2 = atomicAdd(&hE[be], 1) + bE[be];
            if (s2 < ECAP)
                bin_e[((size_t)g * EBUCK + be) * ECAP + s2] = (vs[i] & 31) | (us[i] << 5);
        }
    }
}

// ---------------------------------------------------------------------------
// group/bucket mapping: affin -> flat grid with XCD-pair group affinity
// ---------------------------------------------------------------------------
static __device__ __forceinline__ void map_gb(int gbase, int affin, int& g, int& b)
{
    if (affin) {
        int bid = blockIdx.x;
        int xcd = bid & 7;
        g = xcd >> 1;
        b = ((bid >> 3) << 1) | (xcd & 1);
    } else {
        g = gbase + blockIdx.y;
        b = blockIdx.x;
    }
}

// ---------------------------------------------------------------------------
// Entity hop0, bucketed: counting-sort in LDS (wave-parallel prefix scan),
// then per destination row 2x-unrolled quad-slot register accumulation,
// l2norm, bf16 store.
// ---------------------------------------------------------------------------
__global__ __launch_bounds__(256) void agg_entity_b(
    const int* __restrict__ cnt_e, const int* __restrict__ bin_e,
    const ushort* __restrict__ ueh, ushort* __restrict__ ebufh,
    int gbase, int affin)
{
    int g, b;
    map_gb(gbase, affin, g, b);
    int gz = g - gbase;
    __shared__ int wds[ECAP];
    __shared__ int srt[ECAP];
    __shared__ int cnt[32];
    __shared__ int ptr[33];
    __shared__ int cur[32];
    int t = threadIdx.x;
    int count = min(cnt_e[g * EBUCK + b], ECAP);
    const int* bin = bin_e + ((size_t)g * EBUCK + b) * ECAP;
    if (t < 32) cnt[t] = 0;
    __syncthreads();
    for (int i = t; i < count; i += 256) {
        int w_ = bin[i];
        wds[i] = w_;
        atomicAdd(&cnt[w_ & 31], 1);
    }
    __syncthreads();
    if (t < 64) {   // wave 0: parallel exclusive scan of 32 counters
        int lane = t;
        int c = (lane < 32) ? cnt[lane] : 0;
        int val = c;
        #pragma unroll
        for (int off = 1; off < 32; off <<= 1) {
            int y = __shfl_up(val, off, 64);
            if (lane >= off) val += y;
        }
        if (lane < 32) {
            ptr[lane + 1] = val;
            cur[lane] = val - c;
            if (lane == 0) ptr[0] = 0;
        }
    }
    __syncthreads();
    for (int i = t; i < count; i += 256) {
        int w_ = wds[i];
        int pos = atomicAdd(&cur[w_ & 31], 1);
        srt[pos] = w_ >> 5;
    }
    __syncthreads();
    int wv = t >> 6, lane = t & 63, q = lane >> 4, d16 = lane & 15;
    for (int r = wv; r < 32; r += 4) {
        int start = ptr[r], end = ptr[r + 1];
        float a0 = 0.f, a1 = 0.f, a2 = 0.f, a3 = 0.f;
        for (int base = start; base < end; base += 8) {
            int i1 = base + q, i2 = base + 4 + q;
            int s1 = i1 < end ? srt[i1] : -1;
            int s2 = i2 < end ? srt[i2] : -1;
            unsigned x1 = s1 >= 0 ? (unsigned)s1 : 0u;
            unsigned x2 = s2 >= 0 ? (unsigned)s2 : 0u;
            uint2 r1 = *(const uint2*)(ueh + (x1 << 6) + (d16 << 2));
            uint2 r2 = *(const uint2*)(ueh + (x2 << 6) + (d16 << 2));
            if (s1 < 0) { r1.x = 0u; r1.y = 0u; }
            if (s2 < 0) { r2.x = 0u; r2.y = 0u; }
            a0 += u2f(r1.x << 16);
            a1 += u2f(r1.x & 0xFFFF0000u);
            a2 += u2f(r1.y << 16);
            a3 += u2f(r1.y & 0xFFFF0000u);
            a0 += u2f(r2.x << 16);
            a1 += u2f(r2.x & 0xFFFF0000u);
            a2 += u2f(r2.y << 16);
            a3 += u2f(r2.y & 0xFFFF0000u);
        }
        a0 += __shfl_xor(a0, 16); a0 += __shfl_xor(a0, 32);
        a1 += __shfl_xor(a1, 16); a1 += __shfl_xor(a1, 32);
        a2 += __shfl_xor(a2, 16); a2 += __shfl_xor(a2, 32);
        a3 += __shfl_xor(a3, 16); a3 += __shfl_xor(a3, 32);
        float ss = a0 * a0 + a1 * a1 + a2 * a2 + a3 * a3;
        #pragma unroll
        for (int off = 1; off < 16; off <<= 1) ss += __shfl_xor(ss, off);
        float inv = 1.0f / fmaxf(sqrtf(ss), 1e-12f);
        if (lane < 16) {
            ushort4 o;
            o.x = f2bf(a0 * inv); o.y = f2bf(a1 * inv);
            o.z = f2bf(a2 * inv); o.w = f2bf(a3 * inv);
            *(ushort4*)(ebufh + (size_t)gz * N_ENTITIES * EMB
                        + (((size_t)b * 32 + r) << 6) + (d16 << 2)) = o;
        }
    }
}

// ---------------------------------------------------------------------------
// User hop0+hop1 fused, bucketed: counting-sort (wave scan), then per row
// 2x-unrolled dual gather of eeh and ebufh; acc = norm(A) + norm(B).
// ---------------------------------------------------------------------------
__global__ __launch_bounds__(256) void agg_user_b(
    const int* __restrict__ cnt_u, const int* __restrict__ bin_u,
    const ushort* __restrict__ eeh, const ushort* __restrict__ ebufh,
    float* __restrict__ acc, int gbase, int affin)
{
    int g, b;
    map_gb(gbase, affin, g, b);
    int gz = g - gbase;
    __shared__ int wds[UCAP];
    __shared__ int srt[UCAP];
    __shared__ int cnt[16];
    __shared__ int ptr[17];
    __shared__ int cur[16];
    int t = threadIdx.x;
    int count = min(cnt_u[g * UBUCK + b], UCAP);
    const int* bin = bin_u + ((size_t)g * UBUCK + b) * UCAP;
    const ushort* tabB = ebufh + (size_t)gz * N_ENTITIES * EMB;
    if (t < 16) cnt[t] = 0;
    __syncthreads();
    for (int i = t; i < count; i += 256) {
        int w_ = bin[i];
        wds[i] = w_;
        atomicAdd(&cnt[w_ & 15], 1);
    }
    __syncthreads();
    if (t < 64) {   // wave 0: parallel exclusive scan of 16 counters
        int lane = t;
        int c = (lane < 16) ? cnt[lane] : 0;
        int val = c;
        #pragma unroll
        for (int off = 1; off < 16; off <<= 1) {
            int y = __shfl_up(val, off, 64);
            if (lane >= off) val += y;
        }
        if (lane < 16) {
            ptr[lane + 1] = val;
            cur[lane] = val - c;
            if (lane == 0) ptr[0] = 0;
        }
    }
    __syncthreads();
    for (int i = t; i < count; i += 256) {
        int w_ = wds[i];
        int pos = atomicAdd(&cur[w_ & 15], 1);
        srt[pos] = w_ >> 4;
    }
    __syncthreads();
    int wv = t >> 6, lane = t & 63, q = lane >> 4, d16 = lane & 15;
    for (int r = wv; r < 16; r += 4) {
        int start = ptr[r], end = ptr[r + 1];
        float a0 = 0.f, a1 = 0.f, a2 = 0.f, a3 = 0.f;
        float b0 = 0.f, b1_ = 0.f, b2_ = 0.f, b3 = 0.f;
        for (int base = start; base < end; base += 8) {
            int i1 = base + q, i2 = base + 4 + q;
            int s1 = i1 < end ? srt[i1] : -1;
            int s2 = i2 < end ? srt[i2] : -1;
            unsigned o1 = ((s1 >= 0 ? (unsigned)s1 : 0u) << 6) + (d16 << 2);
            unsigned o2 = ((s2 >= 0 ? (unsigned)s2 : 0u) << 6) + (d16 << 2);
            uint2 ra1 = *(const uint2*)(eeh + o1);
            uint2 rb1 = *(const uint2*)(tabB + o1);
            uint2 ra2 = *(const uint2*)(eeh + o2);
            uint2 rb2 = *(const uint2*)(tabB + o2);
            if (s1 < 0) { ra1.x = 0u; ra1.y = 0u; rb1.x = 0u; rb1.y = 0u; }
            if (s2 < 0) { ra2.x = 0u; ra2.y = 0u; rb2.x = 0u; rb2.y = 0u; }
            a0 += u2f(ra1.x << 16) + u2f(ra2.x << 16);
            a1 += u2f(ra1.x & 0xFFFF0000u) + u2f(ra2.x & 0xFFFF0000u);
            a2 += u2f(ra1.y << 16) + u2f(ra2.y << 16);
            a3 += u2f(ra1.y & 0xFFFF0000u) + u2f(ra2.y & 0xFFFF0000u);
            b0  += u2f(rb1.x << 16) + u2f(rb2.x << 16);
            b1_ += u2f(rb1.x & 0xFFFF0000u) + u2f(rb2.x & 0xFFFF0000u);
            b2_ += u2f(rb1.y << 16) + u2f(rb2.y << 16);
            b3  += u2f(rb1.y & 0xFFFF0000u) + u2f(rb2.y & 0xFFFF0000u);
        }
        a0 += __shfl_xor(a0, 16); a0 += __shfl_xor(a0, 32);
        a1 += __shfl_xor(a1, 16); a1 += __shfl_xor(a1, 32);
        a2 += __shfl_xor(a2, 16); a2 += __shfl_xor(a2, 32);
        a3 += __shfl_xor(a3, 16); a3 += __shfl_xor(a3, 32);
        b0  += __shfl_xor(b0, 16);  b0  += __shfl_xor(b0, 32);
        b1_ += __shfl_xor(b1_, 16); b1_ += __shfl_xor(b1_, 32);
        b2_ += __shfl_xor(b2_, 16); b2_ += __shfl_xor(b2_, 32);
        b3  += __shfl_xor(b3, 16);  b3  += __shfl_xor(b3, 32);
        float ssA = a0 * a0 + a1 * a1 + a2 * a2 + a3 * a3;
        float ssB = b0 * b0 + b1_ * b1_ + b2_ * b2_ + b3 * b3;
        #pragma unroll
        for (int off = 1; off < 16; off <<= 1) {
            ssA += __shfl_xor(ssA, off);
            ssB += __shfl_xor(ssB, off);
        }
        float invA = 1.0f / fmaxf(sqrtf(ssA), 1e-12f);
        float invB = 1.0f / fmaxf(sqrtf(ssB), 1e-12f);
        if (lane < 16) {
            float4 o;
            o.x = a0 * invA + b0 * invB;
            o.y = a1 * invA + b1_ * invB;
            o.z = a2 * invA + b2_ * invB;
            o.w = a3 * invA + b3 * invB;
            *(float4*)(acc + (size_t)g * N_USERS * EMB
                       + (((size_t)b * 16 + r) << 6) + (d16 << 2)) = o;
        }
    }
}

// ---------------------------------------------------------------------------
// Fused: attention-combine -> out_user; proj+normalize of (uie, out_user)
// -> bf16 p1h/p2h; diag = 2*dot(n0,n1).
// ---------------------------------------------------------------------------
__global__ __launch_bounds__(256) void combine_proj(
    const float* __restrict__ acc, const float* __restrict__ uie,
    const float* __restrict__ uemb,
    const float* __restrict__ W1, const float* __restrict__ b1,
    const float* __restrict__ W2, const float* __restrict__ b2,
    float* __restrict__ out_user,
    ushort* __restrict__ p1h, ushort* __restrict__ p2h,
    float* __restrict__ diag)
{
    __shared__ float W1s[EMB * EMB];
    __shared__ float W2s[EMB * EMB];
    __shared__ float zs[4][2][EMB];
    __shared__ float hs[4][2][EMB];
    int t = threadIdx.x;
    for (int i = t; i < EMB * EMB; i += 256) { W1s[i] = W1[i]; W2s[i] = W2[i]; }
    int w = t >> 6, lane = t & 63;
    int u = blockIdx.x * 4 + w;

    float ue = uie[(u << 6) + lane];
    float av[N_GROUPS], s[N_GROUPS];
    #pragma unroll
    for (int g = 0; g < N_GROUPS; ++g) {
        av[g] = acc[(size_t)g * N_USERS * EMB + (u << 6) + lane];
        float p = av[g] * ue;
        #pragma unroll
        for (int off = 1; off < 64; off <<= 1) p += __shfl_xor(p, off);
        s[g] = p;
    }
    float m = fmaxf(fmaxf(s[0], s[1]), fmaxf(s[2], s[3]));
    float att[N_GROUPS], tot = 0.f;
    #pragma unroll
    for (int g = 0; g < N_GROUPS; ++g) { att[g] = __expf(s[g] - m); tot += att[g]; }
    float inv = 1.0f / tot;
    float o = uemb[(u << 6) + lane];
    #pragma unroll
    for (int g = 0; g < N_GROUPS; ++g) o += att[g] * inv * av[g];
    out_user[(u << 6) + lane] = o;

    zs[w][0][lane] = ue;
    zs[w][1][lane] = o;
    __syncthreads();
    float h0 = b1[lane], h1 = b1[lane];
    #pragma unroll
    for (int k = 0; k < EMB; ++k) {
        float w1 = W1s[k * EMB + lane];
        h0 = fmaf(zs[w][0][k], w1, h0);
        h1 = fmaf(zs[w][1][k], w1, h1);
    }
    h0 = h0 > 0.f ? h0 : expm1f(h0);
    h1 = h1 > 0.f ? h1 : expm1f(h1);
    hs[w][0][lane] = h0;
    hs[w][1][lane] = h1;
    __syncthreads();
    float y0 = b2[lane], y1 = b2[lane];
    #pragma unroll
    for (int k = 0; k < EMB; ++k) {
        float w2 = W2s[k * EMB + lane];
        y0 = fmaf(hs[w][0][k], w2, y0);
        y1 = fmaf(hs[w][1][k], w2, y1);
    }
    float ss0 = y0 * y0, ss1 = y1 * y1;
    #pragma unroll
    for (int off = 1; off < 64; off <<= 1) {
        ss0 += __shfl_xor(ss0, off);
        ss1 += __shfl_xor(ss1, off);
    }
    float n0 = y0 / fmaxf(sqrtf(ss0), 1e-12f);
    float n1 = y1 / fmaxf(sqrtf(ss1), 1e-12f);
    p1h[(u << 6) + lane] = f2bf(n0);
    p2h[(u << 6) + lane] = f2bf(n1);
    float d = n0 * n1;
    #pragma unroll
    for (int off = 1; off < 64; off <<= 1) d += __shfl_xor(d, off);
    if (lane == 0) diag[u] = d * 2.0f;
}

// ---------------------------------------------------------------------------
// Tiled MFMA LSE (block-cooperative, LDS-staged B).
// Block = 4 waves = 128 rows x 160 cols. B staged in LDS (stride-68 rows).
// Column sums now combined across the block's 4 waves through LDS and
// written once per block: colp[rb][8000], rb < 63. No early return (ghost
// strips predicated) so all waves reach the barriers.
// ---------------------------------------------------------------------------
#define NCHUNK 50
__global__ __launch_bounds__(256) void lse_tile(
    const ushort* __restrict__ Ah, const ushort* __restrict__ Bh,
    float* __restrict__ rowp, float* __restrict__ colp)
{
    __shared__ ushort Bs[160 * 68];
    __shared__ float cw[4][160];
    int t = threadIdx.x;
    int cb = blockIdx.x % 50;
    int rb = blockIdx.x / 50;
    int j0 = cb * 160;
    for (int slot = t; slot < 1280; slot += 256) {
        int row = slot >> 3;
        int o8 = (slot & 7) << 3;
        uint4 v = *(const uint4*)(Bh + (size_t)(j0 + row) * 64 + o8);
        ushort* dst = Bs + row * 68 + o8;
        *(uint2*)(dst + 0) = make_uint2(v.x, v.y);
        *(uint2*)(dst + 4) = make_uint2(v.z, v.w);
    }
    __syncthreads();
    int w = t >> 6, lane = t & 63;
    int strip = rb * 4 + w;
    bool alive = strip < 250;
    int i0 = alive ? strip * 32 : 0;
    int hl = lane >> 5, l31 = lane & 31;

    const bf16x8* A8 = (const bf16x8*)Ah;
    bf16x8 afrag[4];
    #pragma unroll
    for (int m = 0; m < 4; ++m)
        afrag[m] = A8[(i0 + l31) * 8 + m * 2 + hl];

    float rowacc[16];
    #pragma unroll
    for (int r = 0; r < 16; ++r) rowacc[r] = 0.f;

    #pragma unroll
    for (int cs = 0; cs < 5; ++cs) {
        bf16x8 bfrag[4];
        #pragma unroll
        for (int m = 0; m < 4; ++m) {
            const ushort* p = Bs + (cs * 32 + l31) * 68 + m * 16 + hl * 8;
            union { uint2 u[2]; bf16x8 f; } cv;
            cv.u[0] = *(const uint2*)p;
            cv.u[1] = *(const uint2*)(p + 4);
            bfrag[m] = cv.f;
        }
        f32x16 acc;
        #pragma unroll
        for (int r = 0; r < 16; ++r) acc[r] = 0.f;
        #pragma unroll
        for (int m = 0; m < 4; ++m)
            acc = __builtin_amdgcn_mfma_f32_32x32x16_bf16(afrag[m], bfrag[m], acc, 0, 0, 0);
        float e[16];
        #pragma unroll
        for (int r = 0; r < 16; ++r) {
            e[r] = __expf(acc[r] * 2.0f);
            rowacc[r] += e[r];
        }
        float c01 = (e[0] + e[1]) + (e[2] + e[3]);
        float c23 = (e[4] + e[5]) + (e[6] + e[7]);
        float c45 = (e[8] + e[9]) + (e[10] + e[11]);
        float c67 = (e[12] + e[13]) + (e[14] + e[15]);
        float csum = (c01 + c23) + (c45 + c67);
        csum += __shfl_xor(csum, 32);
        if (!alive) csum = 0.f;
        if (lane < 32) cw[w][cs * 32 + lane] = csum;
    }
    __syncthreads();
    if (t < 160)
        colp[rb * 8000 + j0 + t] = (cw[0][t] + cw[1][t]) + (cw[2][t] + cw[3][t]);
    if (alive) {
        #pragma unroll
        for (int r = 0; r < 16; ++r) {
            float v = rowacc[r];
            #pragma unroll
            for (int off = 1; off < 32; off <<= 1) v += __shfl_xor(v, off);
            if (l31 == 0)
                rowp[cb * 8000 + i0 + (r & 3) + 8 * (r >> 2) + 4 * hl] = v;
        }
    }
}

// ---------------------------------------------------------------------------
// se_row[i] = sum_c rowp[c][i]; se_col[j] = sum_rb colp[rb][j]
// ---------------------------------------------------------------------------
__global__ __launch_bounds__(256) void reduce_partials(
    const float* __restrict__ rowp, const float* __restrict__ colp,
    float* __restrict__ se_row, float* __restrict__ se_col)
{
    int id = blockIdx.x * 256 + threadIdx.x;
    if (id < N_USERS) {
        float s = 0.f;
        for (int c = 0; c < NCHUNK; ++c) s += rowp[c * 8000 + id];
        se_row[id] = s;
    } else if (id < 2 * N_USERS) {
        int j = id - N_USERS;
        float s = 0.f;
        for (int rb = 0; rb < NRB; ++rb) s += colp[rb * 8000 + j];
        se_col[j] = s;
    }
}

// ---------------------------------------------------------------------------
// loss = mean_i( 0.5*(log(se_row)+log(se_col)) - diag )
// ---------------------------------------------------------------------------
__global__ __launch_bounds__(256) void loss_kernel(
    const float* __restrict__ se_row, const float* __restrict__ se_col,
    const float* __restrict__ diag, float* __restrict__ out)
{
    __shared__ float red[256];
    int t = threadIdx.x;
    float s = 0.f;
    for (int i = t; i < N_USERS; i += 256)
        s += 0.5f * (logf(se_row[i]) + logf(se_col[i])) - diag[i];
    red[t] = s;
    __syncthreads();
    for (int w = 128; w > 0; w >>= 1) {
        if (t < w) red[t] += red[t + w];
        __syncthreads();
    }
    if (t == 0) out[0] = red[0] / (float)N_USERS;
}

extern "C" void kernel_launch(void* const* d_in, const int* in_sizes, int n_in,
                              void* d_out, int out_size, void* d_ws, size_t ws_size,
                              hipStream_t stream)
{
    const float* user_emb   = (const float*)d_in[0];
    const float* user_ui    = (const float*)d_in[1];
    const float* entity_emb = (const float*)d_in[2];
    const float* W1 = (const float*)d_in[3];
    const float* b1 = (const float*)d_in[4];
    const float* W2 = (const float*)d_in[5];
    const float* b2 = (const float*)d_in[6];
    const int* ui_index = (const int*)d_in[7];
    const int* ei_index = (const int*)d_in[8];

    float* ws = (float*)d_ws;
    // Layout (float units). Lifetimes stream-ordered; overlays noted.
    float* acc    = ws;                        // [0, 2,048,000) dead after combine_proj
    float* colp   = acc;                       //   overlay: lse col partials (63*8000)
    float* se_row = ws + 2048000;              // 8,000
    float* se_col = se_row + 8000;             // 8,000
    float* diag   = se_col + 8000;             // 8,000  (ends 2,072,000)
    ushort* p1h = (ushort*)(ws + 2072000);     // 512,000 ushort
    ushort* p2h = (ushort*)(ws + 2328000);     // 512,000 ushort
    float* rowp = ws + 2584000;                // 50*8000 = 400,000 -> ends 2,984,000
    int* cnt_u = (int*)(ws + 2984000);         // 4*500 = 2,000
    int* cnt_e = cnt_u + N_GROUPS * UBUCK;     // 4*1000 = 4,000 (ends 2,990,000)
    int* bin_u = cnt_e + N_GROUPS * EBUCK;     // 4*500*640 = 1,280,000 (ends 4,270,000)
    int* bin_e = bin_u + N_GROUPS * UBUCK * UCAP; // 4*1000*384 = 1,536,000 (ends 5,806,000)
    ushort* ueh = (ushort*)(ws + 5806000);     // 512,000 ushort (256,000 f)
    ushort* eeh = (ushort*)(ws + 6062000);     // 2,048,000 ushort (ends 7,086,000)
    ushort* ebufh = (ushort*)(ws + 7086000);   // nG * 2,048,000 ushort

    const size_t BASE_F = 7086000;
    int nG = 1;
    if (ws_size >= (BASE_F + 4 * 1024000) * 4) nG = 4;       // 44.7 MB
    else if (ws_size >= (BASE_F + 2 * 1024000) * 4) nG = 2;  // 36.5 MB

    float* out_user = (float*)d_out;           // 512,000
    float* out_loss = out_user + 512000;       // 1

    dim3 b256(256);

    hipMemsetAsync(cnt_u, 0, (size_t)N_GROUPS * (UBUCK + EBUCK) * 4, stream);
    convert_tables<<<2500, b256, 0, stream>>>(user_emb, entity_emb, ueh, eeh);
    bin_edges<<<dim3((N_EDGES + BIN_CHUNK - 1) / BIN_CHUNK, N_GROUPS), b256, 0, stream>>>(
        ui_index, ei_index, cnt_u, cnt_e, bin_u, bin_e);

    if (nG == 4) {
        // flat grids with XCD-pair group affinity
        agg_entity_b<<<EBUCK * 4, b256, 0, stream>>>(
            cnt_e, bin_e, ueh, ebufh, 0, 1);
        agg_user_b<<<UBUCK * 4, b256, 0, stream>>>(
            cnt_u, bin_u, eeh, ebufh, acc, 0, 1);
    } else {
        for (int gbase = 0; gbase < N_GROUPS; gbase += nG) {
            agg_entity_b<<<dim3(EBUCK, nG), b256, 0, stream>>>(
                cnt_e, bin_e, ueh, ebufh, gbase, 0);
            agg_user_b<<<dim3(UBUCK, nG), b256, 0, stream>>>(
                cnt_u, bin_u, eeh, ebufh, acc, gbase, 0);
        }
    }

    combine_proj<<<N_USERS / 4, b256, 0, stream>>>(
        acc, user_ui, user_emb, W1, b1, W2, b2,
        out_user, p1h, p2h, diag);

    lse_tile<<<NRB * 50, b256, 0, stream>>>(p1h, p2h, rowp, colp);
    reduce_partials<<<(2 * N_USERS + 255) / 256, b256, 0, stream>>>(
        rowp, colp, se_row, se_col);
    loss_kernel<<<1, b256, 0, stream>>>(se_row, se_col, diag, out_loss);
}

// Round 16
// 152.362 us; speedup vs baseline: 1.2055x; 1.0724x over previous
//
#include <hip/hip_runtime.h>
#include <hip/hip_bf16.h>
#include <math.h>

#define N_USERS 8000
#define N_ENTITIES 32000
#define EMB 64
#define N_GROUPS 4
#define N_EDGES 200000

// bucketed adjacency (finer buckets for occupancy; XCD-pair group affinity)
#define UBUCK 500            // 8000 users  / 16 per bucket (mean 400 edges)
#define EBUCK 1000           // 32000 ents  / 32 per bucket (mean 200 edges)
#define UCAP 640             // mean 400, +12 sigma
#define ECAP 384             // mean 200, +13 sigma
#define BIN_CHUNK 2048
#define NRB 63               // lse row-blocks (63 x 4 strips covers 250)
#define NCHUNK 50

typedef __attribute__((ext_vector_type(8))) __bf16 bf16x8;
typedef __attribute__((ext_vector_type(16))) float f32x16;

static __device__ __forceinline__ unsigned short f2bf(float f) {
    union { float f; unsigned int i; } x; x.f = f;
    return (unsigned short)((x.i + 0x7FFF + ((x.i >> 16) & 1)) >> 16);
}
static __device__ __forceinline__ float u2f(unsigned int u) {
    union { unsigned int i; float f; } x; x.i = u; return x.f;
}

// ---------------------------------------------------------------------------
// Convert user_emb / entity_emb to bf16 tables; block 0 also zeros the
// bucket counters (this kernel completes before bin_edges starts).
// ---------------------------------------------------------------------------
__global__ __launch_bounds__(256) void convert_tables(
    const float* __restrict__ ue, const float* __restrict__ ee,
    ushort* __restrict__ ueh, ushort* __restrict__ eeh,
    int* __restrict__ cnt)   // N_GROUPS*(UBUCK+EBUCK) ints
{
    if (blockIdx.x == 0) {
        for (int i = threadIdx.x; i < N_GROUPS * (UBUCK + EBUCK); i += 256)
            cnt[i] = 0;
    }
    int i4 = blockIdx.x * 256 + threadIdx.x;   // float4 units
    if (i4 < 128000) {
        float4 v = ((const float4*)ue)[i4];
        ushort4 o; o.x = f2bf(v.x); o.y = f2bf(v.y); o.z = f2bf(v.z); o.w = f2bf(v.w);
        ((ushort4*)ueh)[i4] = o;
    } else if (i4 < 640000) {
        int j = i4 - 128000;
        float4 v = ((const float4*)ee)[j];
        ushort4 o; o.x = f2bf(v.x); o.y = f2bf(v.y); o.z = f2bf(v.z); o.w = f2bf(v.w);
        ((ushort4*)eeh)[j] = o;
    }
}

// ---------------------------------------------------------------------------
// Destination-bucketed binning, both directions, per group.
// word (user dir):  (u & 15) | (v << 4)   bucket = u >> 4   (500 buckets)
// word (ent  dir):  (v & 31) | (u << 5)   bucket = v >> 5   (1000 buckets)
// ---------------------------------------------------------------------------
__global__ __launch_bounds__(256) void bin_edges(
    const int* __restrict__ ui_index, const int* __restrict__ ei_index,
    int* __restrict__ cnt_u, int* __restrict__ cnt_e,
    int* __restrict__ bin_u, int* __restrict__ bin_e)
{
    int g = blockIdx.y;
    const int* ui = ui_index + (size_t)g * N_EDGES;
    const int* ei = ei_index + (size_t)g * N_EDGES;
    __shared__ int hU[UBUCK], hE[EBUCK], bU[UBUCK], bE[EBUCK];
    int t = threadIdx.x;
    for (int i = t; i < UBUCK; i += 256) hU[i] = 0;
    for (int i = t; i < EBUCK; i += 256) hE[i] = 0;
    __syncthreads();
    int e0 = blockIdx.x * BIN_CHUNK;
    int us[8], vs[8];
    #pragma unroll
    for (int i = 0; i < 8; ++i) {
        int e = e0 + i * 256 + t;
        bool ok = e < N_EDGES;
        us[i] = ok ? ui[e] : -1;
        vs[i] = ok ? ei[e] : 0;
        if (ok) {
            atomicAdd(&hU[us[i] >> 4], 1);
            atomicAdd(&hE[vs[i] >> 5], 1);
        }
    }
    __syncthreads();
    for (int i = t; i < UBUCK; i += 256) {
        int c = hU[i];
        bU[i] = c ? atomicAdd(&cnt_u[g * UBUCK + i], c) : 0;
        hU[i] = 0;
    }
    for (int i = t; i < EBUCK; i += 256) {
        int c = hE[i];
        bE[i] = c ? atomicAdd(&cnt_e[g * EBUCK + i], c) : 0;
        hE[i] = 0;
    }
    __syncthreads();
    #pragma unroll
    for (int i = 0; i < 8; ++i) {
        if (us[i] >= 0) {
            int bu = us[i] >> 4;
            int s = atomicAdd(&hU[bu], 1) + bU[bu];
            if (s < UCAP)
                bin_u[((size_t)g * UBUCK + bu) * UCAP + s] = (us[i] & 15) | (vs[i] << 4);
            int be = vs[i] >> 5;
            int s2 = atomicAdd(&hE[be], 1) + bE[be];
            if (s2 < ECAP)
                bin_e[((size_t)g * EBUCK + be) * ECAP + s2] = (vs[i] & 31) | (us[i] << 5);
        }
    }
}

// ---------------------------------------------------------------------------
// group/bucket mapping: affin -> flat grid with XCD-pair group affinity
// ---------------------------------------------------------------------------
static __device__ __forceinline__ void map_gb(int gbase, int affin, int& g, int& b)
{
    if (affin) {
        int bid = blockIdx.x;
        int xcd = bid & 7;
        g = xcd >> 1;
        b = ((bid >> 3) << 1) | (xcd & 1);
    } else {
        g = gbase + blockIdx.y;
        b = blockIdx.x;
    }
}

// ---------------------------------------------------------------------------
// Entity hop0, bucketed: counting-sort in LDS (wave-parallel prefix scan),
// then per destination row 2x-unrolled quad-slot register accumulation,
// l2norm, bf16 store.
// ---------------------------------------------------------------------------
__global__ __launch_bounds__(256) void agg_entity_b(
    const int* __restrict__ cnt_e, const int* __restrict__ bin_e,
    const ushort* __restrict__ ueh, ushort* __restrict__ ebufh,
    int gbase, int affin)
{
    int g, b;
    map_gb(gbase, affin, g, b);
    int gz = g - gbase;
    __shared__ int wds[ECAP];
    __shared__ int srt[ECAP];
    __shared__ int cnt[32];
    __shared__ int ptr[33];
    __shared__ int cur[32];
    int t = threadIdx.x;
    int count = min(cnt_e[g * EBUCK + b], ECAP);
    const int* bin = bin_e + ((size_t)g * EBUCK + b) * ECAP;
    if (t < 32) cnt[t] = 0;
    __syncthreads();
    for (int i = t; i < count; i += 256) {
        int w_ = bin[i];
        wds[i] = w_;
        atomicAdd(&cnt[w_ & 31], 1);
    }
    __syncthreads();
    if (t < 64) {   // wave 0: parallel exclusive scan of 32 counters
        int lane = t;
        int c = (lane < 32) ? cnt[lane] : 0;
        int val = c;
        #pragma unroll
        for (int off = 1; off < 32; off <<= 1) {
            int y = __shfl_up(val, off, 64);
            if (lane >= off) val += y;
        }
        if (lane < 32) {
            ptr[lane + 1] = val;
            cur[lane] = val - c;
            if (lane == 0) ptr[0] = 0;
        }
    }
    __syncthreads();
    for (int i = t; i < count; i += 256) {
        int w_ = wds[i];
        int pos = atomicAdd(&cur[w_ & 31], 1);
        srt[pos] = w_ >> 5;
    }
    __syncthreads();
    int wv = t >> 6, lane = t & 63, q = lane >> 4, d16 = lane & 15;
    for (int r = wv; r < 32; r += 4) {
        int start = ptr[r], end = ptr[r + 1];
        float a0 = 0.f, a1 = 0.f, a2 = 0.f, a3 = 0.f;
        for (int base = start; base < end; base += 8) {
            int i1 = base + q, i2 = base + 4 + q;
            int s1 = i1 < end ? srt[i1] : -1;
            int s2 = i2 < end ? srt[i2] : -1;
            unsigned x1 = s1 >= 0 ? (unsigned)s1 : 0u;
            unsigned x2 = s2 >= 0 ? (unsigned)s2 : 0u;
            uint2 r1 = *(const uint2*)(ueh + (x1 << 6) + (d16 << 2));
            uint2 r2 = *(const uint2*)(ueh + (x2 << 6) + (d16 << 2));
            if (s1 < 0) { r1.x = 0u; r1.y = 0u; }
            if (s2 < 0) { r2.x = 0u; r2.y = 0u; }
            a0 += u2f(r1.x << 16);
            a1 += u2f(r1.x & 0xFFFF0000u);
            a2 += u2f(r1.y << 16);
            a3 += u2f(r1.y & 0xFFFF0000u);
            a0 += u2f(r2.x << 16);
            a1 += u2f(r2.x & 0xFFFF0000u);
            a2 += u2f(r2.y << 16);
            a3 += u2f(r2.y & 0xFFFF0000u);
        }
        a0 += __shfl_xor(a0, 16); a0 += __shfl_xor(a0, 32);
        a1 += __shfl_xor(a1, 16); a1 += __shfl_xor(a1, 32);
        a2 += __shfl_xor(a2, 16); a2 += __shfl_xor(a2, 32);
        a3 += __shfl_xor(a3, 16); a3 += __shfl_xor(a3, 32);
        float ss = a0 * a0 + a1 * a1 + a2 * a2 + a3 * a3;
        #pragma unroll
        for (int off = 1; off < 16; off <<= 1) ss += __shfl_xor(ss, off);
        float inv = 1.0f / fmaxf(sqrtf(ss), 1e-12f);
        if (lane < 16) {
            ushort4 o;
            o.x = f2bf(a0 * inv); o.y = f2bf(a1 * inv);
            o.z = f2bf(a2 * inv); o.w = f2bf(a3 * inv);
            *(ushort4*)(ebufh + (size_t)gz * N_ENTITIES * EMB
                        + (((size_t)b * 32 + r) << 6) + (d16 << 2)) = o;
        }
    }
}

// ---------------------------------------------------------------------------
// User hop0+hop1 fused, bucketed: counting-sort (wave scan), then per row
// 4x-unrolled dual gather of eeh and ebufh (8 loads in flight);
// acc = norm(A) + norm(B).
// ---------------------------------------------------------------------------
__global__ __launch_bounds__(256) void agg_user_b(
    const int* __restrict__ cnt_u, const int* __restrict__ bin_u,
    const ushort* __restrict__ eeh, const ushort* __restrict__ ebufh,
    float* __restrict__ acc, int gbase, int affin)
{
    int g, b;
    map_gb(gbase, affin, g, b);
    int gz = g - gbase;
    __shared__ int wds[UCAP];
    __shared__ int srt[UCAP];
    __shared__ int cnt[16];
    __shared__ int ptr[17];
    __shared__ int cur[16];
    int t = threadIdx.x;
    int count = min(cnt_u[g * UBUCK + b], UCAP);
    const int* bin = bin_u + ((size_t)g * UBUCK + b) * UCAP;
    const ushort* tabB = ebufh + (size_t)gz * N_ENTITIES * EMB;
    if (t < 16) cnt[t] = 0;
    __syncthreads();
    for (int i = t; i < count; i += 256) {
        int w_ = bin[i];
        wds[i] = w_;
        atomicAdd(&cnt[w_ & 15], 1);
    }
    __syncthreads();
    if (t < 64) {   // wave 0: parallel exclusive scan of 16 counters
        int lane = t;
        int c = (lane < 16) ? cnt[lane] : 0;
        int val = c;
        #pragma unroll
        for (int off = 1; off < 16; off <<= 1) {
            int y = __shfl_up(val, off, 64);
            if (lane >= off) val += y;
        }
        if (lane < 16) {
            ptr[lane + 1] = val;
            cur[lane] = val - c;
            if (lane == 0) ptr[0] = 0;
        }
    }
    __syncthreads();
    for (int i = t; i < count; i += 256) {
        int w_ = wds[i];
        int pos = atomicAdd(&cur[w_ & 15], 1);
        srt[pos] = w_ >> 4;
    }
    __syncthreads();
    int wv = t >> 6, lane = t & 63, q = lane >> 4, d16 = lane & 15;
    for (int r = wv; r < 16; r += 4) {
        int start = ptr[r], end = ptr[r + 1];
        float a0 = 0.f, a1 = 0.f, a2 = 0.f, a3 = 0.f;
        float b0 = 0.f, b1_ = 0.f, b2_ = 0.f, b3 = 0.f;
        for (int base = start; base < end; base += 16) {
            int s0_ = (base + q)      < end ? srt[base + q]      : -1;
            int s1_ = (base + 4 + q)  < end ? srt[base + 4 + q]  : -1;
            int s2_ = (base + 8 + q)  < end ? srt[base + 8 + q]  : -1;
            int s3_ = (base + 12 + q) < end ? srt[base + 12 + q] : -1;
            unsigned o0 = ((s0_ >= 0 ? (unsigned)s0_ : 0u) << 6) + (d16 << 2);
            unsigned o1 = ((s1_ >= 0 ? (unsigned)s1_ : 0u) << 6) + (d16 << 2);
            unsigned o2 = ((s2_ >= 0 ? (unsigned)s2_ : 0u) << 6) + (d16 << 2);
            unsigned o3 = ((s3_ >= 0 ? (unsigned)s3_ : 0u) << 6) + (d16 << 2);
            uint2 ra0 = *(const uint2*)(eeh + o0);
            uint2 rb0 = *(const uint2*)(tabB + o0);
            uint2 ra1 = *(const uint2*)(eeh + o1);
            uint2 rb1 = *(const uint2*)(tabB + o1);
            uint2 ra2 = *(const uint2*)(eeh + o2);
            uint2 rb2 = *(const uint2*)(tabB + o2);
            uint2 ra3 = *(const uint2*)(eeh + o3);
            uint2 rb3 = *(const uint2*)(tabB + o3);
            if (s0_ < 0) { ra0.x = ra0.y = rb0.x = rb0.y = 0u; }
            if (s1_ < 0) { ra1.x = ra1.y = rb1.x = rb1.y = 0u; }
            if (s2_ < 0) { ra2.x = ra2.y = rb2.x = rb2.y = 0u; }
            if (s3_ < 0) { ra3.x = ra3.y = rb3.x = rb3.y = 0u; }
            a0 += (u2f(ra0.x << 16) + u2f(ra1.x << 16))
                + (u2f(ra2.x << 16) + u2f(ra3.x << 16));
            a1 += (u2f(ra0.x & 0xFFFF0000u) + u2f(ra1.x & 0xFFFF0000u))
                + (u2f(ra2.x & 0xFFFF0000u) + u2f(ra3.x & 0xFFFF0000u));
            a2 += (u2f(ra0.y << 16) + u2f(ra1.y << 16))
                + (u2f(ra2.y << 16) + u2f(ra3.y << 16));
            a3 += (u2f(ra0.y & 0xFFFF0000u) + u2f(ra1.y & 0xFFFF0000u))
                + (u2f(ra2.y & 0xFFFF0000u) + u2f(ra3.y & 0xFFFF0000u));
            b0  += (u2f(rb0.x << 16) + u2f(rb1.x << 16))
                 + (u2f(rb2.x << 16) + u2f(rb3.x << 16));
            b1_ += (u2f(rb0.x & 0xFFFF0000u) + u2f(rb1.x & 0xFFFF0000u))
                 + (u2f(rb2.x & 0xFFFF0000u) + u2f(rb3.x & 0xFFFF0000u));
            b2_ += (u2f(rb0.y << 16) + u2f(rb1.y << 16))
                 + (u2f(rb2.y << 16) + u2f(rb3.y << 16));
            b3  += (u2f(rb0.y & 0xFFFF0000u) + u2f(rb1.y & 0xFFFF0000u))
                 + (u2f(rb2.y & 0xFFFF0000u) + u2f(rb3.y & 0xFFFF0000u));
        }
        a0 += __shfl_xor(a0, 16); a0 += __shfl_xor(a0, 32);
        a1 += __shfl_xor(a1, 16); a1 += __shfl_xor(a1, 32);
        a2 += __shfl_xor(a2, 16); a2 += __shfl_xor(a2, 32);
        a3 += __shfl_xor(a3, 16); a3 += __shfl_xor(a3, 32);
        b0  += __shfl_xor(b0, 16);  b0  += __shfl_xor(b0, 32);
        b1_ += __shfl_xor(b1_, 16); b1_ += __shfl_xor(b1_, 32);
        b2_ += __shfl_xor(b2_, 16); b2_ += __shfl_xor(b2_, 32);
        b3  += __shfl_xor(b3, 16);  b3  += __shfl_xor(b3, 32);
        float ssA = a0 * a0 + a1 * a1 + a2 * a2 + a3 * a3;
        float ssB = b0 * b0 + b1_ * b1_ + b2_ * b2_ + b3 * b3;
        #pragma unroll
        for (int off = 1; off < 16; off <<= 1) {
            ssA += __shfl_xor(ssA, off);
            ssB += __shfl_xor(ssB, off);
        }
        float invA = 1.0f / fmaxf(sqrtf(ssA), 1e-12f);
        float invB = 1.0f / fmaxf(sqrtf(ssB), 1e-12f);
        if (lane < 16) {
            float4 o;
            o.x = a0 * invA + b0 * invB;
            o.y = a1 * invA + b1_ * invB;
            o.z = a2 * invA + b2_ * invB;
            o.w = a3 * invA + b3 * invB;
            *(float4*)(acc + (size_t)g * N_USERS * EMB
                       + (((size_t)b * 16 + r) << 6) + (d16 << 2)) = o;
        }
    }
}

// ---------------------------------------------------------------------------
// Fused: attention-combine -> out_user; proj+normalize of (uie, out_user)
// -> bf16 p1h/p2h; diag = 2*dot(n0,n1). Block 0 zeroes out_loss for the
// later finish_loss atomics (stream-ordered).
// ---------------------------------------------------------------------------
__global__ __launch_bounds__(256) void combine_proj(
    const float* __restrict__ acc, const float* __restrict__ uie,
    const float* __restrict__ uemb,
    const float* __restrict__ W1, const float* __restrict__ b1,
    const float* __restrict__ W2, const float* __restrict__ b2,
    float* __restrict__ out_user,
    ushort* __restrict__ p1h, ushort* __restrict__ p2h,
    float* __restrict__ diag, float* __restrict__ out_loss)
{
    __shared__ float W1s[EMB * EMB];
    __shared__ float W2s[EMB * EMB];
    __shared__ float zs[4][2][EMB];
    __shared__ float hs[4][2][EMB];
    int t = threadIdx.x;
    if (blockIdx.x == 0 && t == 0) out_loss[0] = 0.f;
    for (int i = t; i < EMB * EMB; i += 256) { W1s[i] = W1[i]; W2s[i] = W2[i]; }
    int w = t >> 6, lane = t & 63;
    int u = blockIdx.x * 4 + w;

    float ue = uie[(u << 6) + lane];
    float av[N_GROUPS], s[N_GROUPS];
    #pragma unroll
    for (int g = 0; g < N_GROUPS; ++g) {
        av[g] = acc[(size_t)g * N_USERS * EMB + (u << 6) + lane];
        float p = av[g] * ue;
        #pragma unroll
        for (int off = 1; off < 64; off <<= 1) p += __shfl_xor(p, off);
        s[g] = p;
    }
    float m = fmaxf(fmaxf(s[0], s[1]), fmaxf(s[2], s[3]));
    float att[N_GROUPS], tot = 0.f;
    #pragma unroll
    for (int g = 0; g < N_GROUPS; ++g) { att[g] = __expf(s[g] - m); tot += att[g]; }
    float inv = 1.0f / tot;
    float o = uemb[(u << 6) + lane];
    #pragma unroll
    for (int g = 0; g < N_GROUPS; ++g) o += att[g] * inv * av[g];
    out_user[(u << 6) + lane] = o;

    zs[w][0][lane] = ue;
    zs[w][1][lane] = o;
    __syncthreads();
    float h0 = b1[lane], h1 = b1[lane];
    #pragma unroll
    for (int k = 0; k < EMB; ++k) {
        float w1 = W1s[k * EMB + lane];
        h0 = fmaf(zs[w][0][k], w1, h0);
        h1 = fmaf(zs[w][1][k], w1, h1);
    }
    h0 = h0 > 0.f ? h0 : expm1f(h0);
    h1 = h1 > 0.f ? h1 : expm1f(h1);
    hs[w][0][lane] = h0;
    hs[w][1][lane] = h1;
    __syncthreads();
    float y0 = b2[lane], y1 = b2[lane];
    #pragma unroll
    for (int k = 0; k < EMB; ++k) {
        float w2 = W2s[k * EMB + lane];
        y0 = fmaf(hs[w][0][k], w2, y0);
        y1 = fmaf(hs[w][1][k], w2, y1);
    }
    float ss0 = y0 * y0, ss1 = y1 * y1;
    #pragma unroll
    for (int off = 1; off < 64; off <<= 1) {
        ss0 += __shfl_xor(ss0, off);
        ss1 += __shfl_xor(ss1, off);
    }
    float n0 = y0 / fmaxf(sqrtf(ss0), 1e-12f);
    float n1 = y1 / fmaxf(sqrtf(ss1), 1e-12f);
    p1h[(u << 6) + lane] = f2bf(n0);
    p2h[(u << 6) + lane] = f2bf(n1);
    float d = n0 * n1;
    #pragma unroll
    for (int off = 1; off < 64; off <<= 1) d += __shfl_xor(d, off);
    if (lane == 0) diag[u] = d * 2.0f;
}

// ---------------------------------------------------------------------------
// Tiled MFMA LSE (block-cooperative, LDS-staged B).
// Block = 4 waves = 128 rows x 160 cols. B staged in LDS (stride-68 rows).
// Column sums combined across the block's 4 waves -> colp[rb][8000], rb<63.
// ---------------------------------------------------------------------------
__global__ __launch_bounds__(256) void lse_tile(
    const ushort* __restrict__ Ah, const ushort* __restrict__ Bh,
    float* __restrict__ rowp, float* __restrict__ colp)
{
    __shared__ ushort Bs[160 * 68];
    __shared__ float cw[4][160];
    int t = threadIdx.x;
    int cb = blockIdx.x % 50;
    int rb = blockIdx.x / 50;
    int j0 = cb * 160;
    for (int slot = t; slot < 1280; slot += 256) {
        int row = slot >> 3;
        int o8 = (slot & 7) << 3;
        uint4 v = *(const uint4*)(Bh + (size_t)(j0 + row) * 64 + o8);
        ushort* dst = Bs + row * 68 + o8;
        *(uint2*)(dst + 0) = make_uint2(v.x, v.y);
        *(uint2*)(dst + 4) = make_uint2(v.z, v.w);
    }
    __syncthreads();
    int w = t >> 6, lane = t & 63;
    int strip = rb * 4 + w;
    bool alive = strip < 250;
    int i0 = alive ? strip * 32 : 0;
    int hl = lane >> 5, l31 = lane & 31;

    const bf16x8* A8 = (const bf16x8*)Ah;
    bf16x8 afrag[4];
    #pragma unroll
    for (int m = 0; m < 4; ++m)
        afrag[m] = A8[(i0 + l31) * 8 + m * 2 + hl];

    float rowacc[16];
    #pragma unroll
    for (int r = 0; r < 16; ++r) rowacc[r] = 0.f;

    #pragma unroll
    for (int cs = 0; cs < 5; ++cs) {
        bf16x8 bfrag[4];
        #pragma unroll
        for (int m = 0; m < 4; ++m) {
            const ushort* p = Bs + (cs * 32 + l31) * 68 + m * 16 + hl * 8;
            union { uint2 u[2]; bf16x8 f; } cv;
            cv.u[0] = *(const uint2*)p;
            cv.u[1] = *(const uint2*)(p + 4);
            bfrag[m] = cv.f;
        }
        f32x16 acc;
        #pragma unroll
        for (int r = 0; r < 16; ++r) acc[r] = 0.f;
        #pragma unroll
        for (int m = 0; m < 4; ++m)
            acc = __builtin_amdgcn_mfma_f32_32x32x16_bf16(afrag[m], bfrag[m], acc, 0, 0, 0);
        float e[16];
        #pragma unroll
        for (int r = 0; r < 16; ++r) {
            e[r] = __expf(acc[r] * 2.0f);
            rowacc[r] += e[r];
        }
        float c01 = (e[0] + e[1]) + (e[2] + e[3]);
        float c23 = (e[4] + e[5]) + (e[6] + e[7]);
        float c45 = (e[8] + e[9]) + (e[10] + e[11]);
        float c67 = (e[12] + e[13]) + (e[14] + e[15]);
        float csum = (c01 + c23) + (c45 + c67);
        csum += __shfl_xor(csum, 32);
        if (!alive) csum = 0.f;
        if (lane < 32) cw[w][cs * 32 + lane] = csum;
    }
    __syncthreads();
    if (t < 160)
        colp[rb * 8000 + j0 + t] = (cw[0][t] + cw[1][t]) + (cw[2][t] + cw[3][t]);
    if (alive) {
        #pragma unroll
        for (int r = 0; r < 16; ++r) {
            float v = rowacc[r];
            #pragma unroll
            for (int off = 1; off < 32; off <<= 1) v += __shfl_xor(v, off);
            if (l31 == 0)
                rowp[cb * 8000 + i0 + (r & 3) + 8 * (r >> 2) + 4 * hl] = v;
        }
    }
}

// ---------------------------------------------------------------------------
// finish_loss: per user fold rowp (50) + colp (63) partials and diag;
// block-reduce; atomicAdd(out_loss, partial/N). out_loss zeroed upstream.
// ---------------------------------------------------------------------------
__global__ __launch_bounds__(256) void finish_loss(
    const float* __restrict__ rowp, const float* __restrict__ colp,
    const float* __restrict__ diag, float* __restrict__ out_loss)
{
    int t = threadIdx.x;
    int id = blockIdx.x * 256 + t;
    float s = 0.f;
    if (id < N_USERS) {
        float sr = 0.f, sc = 0.f;
        for (int c = 0; c < NCHUNK; ++c) sr += rowp[c * 8000 + id];
        for (int rb = 0; rb < NRB; ++rb) sc += colp[rb * 8000 + id];
        s = 0.5f * (logf(sr) + logf(sc)) - diag[id];
    }
    __shared__ float red[256];
    red[t] = s;
    __syncthreads();
    for (int w = 128; w > 0; w >>= 1) {
        if (t < w) red[t] += red[t + w];
        __syncthreads();
    }
    if (t == 0) atomicAdd(out_loss, red[0] * (1.0f / (float)N_USERS));
}

extern "C" void kernel_launch(void* const* d_in, const int* in_sizes, int n_in,
                              void* d_out, int out_size, void* d_ws, size_t ws_size,
                              hipStream_t stream)
{
    const float* user_emb   = (const float*)d_in[0];
    const float* user_ui    = (const float*)d_in[1];
    const float* entity_emb = (const float*)d_in[2];
    const float* W1 = (const float*)d_in[3];
    const float* b1 = (const float*)d_in[4];
    const float* W2 = (const float*)d_in[5];
    const float* b2 = (const float*)d_in[6];
    const int* ui_index = (const int*)d_in[7];
    const int* ei_index = (const int*)d_in[8];

    float* ws = (float*)d_ws;
    // Layout (float units). Lifetimes stream-ordered; overlays noted.
    float* acc    = ws;                        // [0, 2,048,000) dead after combine_proj
    float* colp   = acc;                       //   overlay: lse col partials (63*8000)
    float* diag   = ws + 2048000;              // 8,000 (ends 2,056,000)
    ushort* p1h = (ushort*)(ws + 2072000);     // 512,000 ushort
    ushort* p2h = (ushort*)(ws + 2328000);     // 512,000 ushort
    float* rowp = ws + 2584000;                // 50*8000 = 400,000 -> ends 2,984,000
    int* cnt_u = (int*)(ws + 2984000);         // 4*500 = 2,000
    int* cnt_e = cnt_u + N_GROUPS * UBUCK;     // 4*1000 = 4,000 (ends 2,990,000)
    int* bin_u = cnt_e + N_GROUPS * EBUCK;     // 4*500*640 = 1,280,000 (ends 4,270,000)
    int* bin_e = bin_u + N_GROUPS * UBUCK * UCAP; // 4*1000*384 = 1,536,000 (ends 5,806,000)
    ushort* ueh = (ushort*)(ws + 5806000);     // 512,000 ushort (256,000 f)
    ushort* eeh = (ushort*)(ws + 6062000);     // 2,048,000 ushort (ends 7,086,000)
    ushort* ebufh = (ushort*)(ws + 7086000);   // nG * 2,048,000 ushort

    const size_t BASE_F = 7086000;
    int nG = 1;
    if (ws_size >= (BASE_F + 4 * 1024000) * 4) nG = 4;       // 44.7 MB
    else if (ws_size >= (BASE_F + 2 * 1024000) * 4) nG = 2;  // 36.5 MB

    float* out_user = (float*)d_out;           // 512,000
    float* out_loss = out_user + 512000;       // 1

    dim3 b256(256);

    convert_tables<<<2500, b256, 0, stream>>>(user_emb, entity_emb, ueh, eeh, cnt_u);
    bin_edges<<<dim3((N_EDGES + BIN_CHUNK - 1) / BIN_CHUNK, N_GROUPS), b256, 0, stream>>>(
        ui_index, ei_index, cnt_u, cnt_e, bin_u, bin_e);

    if (nG == 4) {
        // flat grids with XCD-pair group affinity
        agg_entity_b<<<EBUCK * 4, b256, 0, stream>>>(
            cnt_e, bin_e, ueh, ebufh, 0, 1);
        agg_user_b<<<UBUCK * 4, b256, 0, stream>>>(
            cnt_u, bin_u, eeh, ebufh, acc, 0, 1);
    } else {
        for (int gbase = 0; gbase < N_GROUPS; gbase += nG) {
            agg_entity_b<<<dim3(EBUCK, nG), b256, 0, stream>>>(
                cnt_e, bin_e, ueh, ebufh, gbase, 0);
            agg_user_b<<<dim3(UBUCK, nG), b256, 0, stream>>>(
                cnt_u, bin_u, eeh, ebufh, acc, gbase, 0);
        }
    }

    combine_proj<<<N_USERS / 4, b256, 0, stream>>>(
        acc, user_ui, user_emb, W1, b1, W2, b2,
        out_user, p1h, p2h, diag, out_loss);

    lse_tile<<<NRB * 50, b256, 0, stream>>>(p1h, p2h, rowp, colp);
    finish_loss<<<(N_USERS + 255) / 256, b256, 0, stream>>>(
        rowp, colp, diag, out_loss);
}